// Round 3
// baseline (290.526 us; speedup 1.0000x reference)
//
#include <hip/hip_runtime.h>
#include <hip/hip_bf16.h>

#define BB 32
#define INP 1024
#define WIDTH 256
#define OUTP 1024
#define NE 8
#define HW 196
#define HH 14
#define EPS 1e-5f

#define S1 (WIDTH * INP)        // 262144
#define S2 (WIDTH * WIDTH * 9)  // 589824
#define S3 (OUTP * WIDTH)       // 262144

typedef __attribute__((ext_vector_type(8))) short bf16x8;
typedef __attribute__((ext_vector_type(4))) float f32x4;
typedef __attribute__((ext_vector_type(8))) unsigned short u16x8;

// Swizzled operand layout: tile = 16 rows x 32 k = 512 bf16 = 1 KB.
// Element (r,k) at lane*8 + (k&7), lane = (r&15) | (((k>>3)&3)<<4).

__device__ __forceinline__ unsigned short f2bf_bits(float f) {
    unsigned u = __float_as_uint(f);
    u += 0x7FFFu + ((u >> 16) & 1u);   // RNE
    return (unsigned short)(u >> 16);
}
__device__ __forceinline__ float bf2f(unsigned short h) {
    return __uint_as_float((unsigned)h << 16);
}

#if defined(__has_builtin)
#if __has_builtin(__builtin_amdgcn_global_load_lds)
#define HAVE_GLL 1
#endif
#endif
__device__ __forceinline__ void gl2lds(const unsigned short* g, unsigned short* l,
                                       int lane) {
#ifdef HAVE_GLL
    __builtin_amdgcn_global_load_lds(
        (const __attribute__((address_space(1))) unsigned int*)(const void*)g,
        (__attribute__((address_space(3))) unsigned int*)(void*)l, 16, 0, 0);
#else
    *(u16x8*)(l + lane * 8) = *(const u16x8*)g;
#endif
}

// ---------------------------------------------------------------------------
// In-block routing (8-sample group g): srw[s*8+e] = sigmoid(scale*(v@W)+b).
// Leading __syncthreads makes it safe to call in a g-loop (WAR on srw).
// ---------------------------------------------------------------------------
__device__ __forceinline__ void block_route(
    const float* __restrict__ vec, const float* __restrict__ W,
    const float* __restrict__ bias, float scale, int C, int g,
    float* srw, int tid) {
    __syncthreads();
    int wv = tid >> 6, lane = tid & 63;
    float p0[NE], p1[NE];
#pragma unroll
    for (int e = 0; e < NE; e++) { p0[e] = 0.f; p1[e] = 0.f; }
    const float* v0 = vec + (size_t)(g * 8 + wv * 2) * C;
    const float* v1 = v0 + C;
    for (int c = lane; c < C; c += 64) {
        float4 wa = *(const float4*)(W + c * 8);
        float4 wb = *(const float4*)(W + c * 8 + 4);
        float m0 = v0[c], m1 = v1[c];
        p0[0] += m0 * wa.x; p0[1] += m0 * wa.y; p0[2] += m0 * wa.z; p0[3] += m0 * wa.w;
        p0[4] += m0 * wb.x; p0[5] += m0 * wb.y; p0[6] += m0 * wb.z; p0[7] += m0 * wb.w;
        p1[0] += m1 * wa.x; p1[1] += m1 * wa.y; p1[2] += m1 * wa.z; p1[3] += m1 * wa.w;
        p1[4] += m1 * wb.x; p1[5] += m1 * wb.y; p1[6] += m1 * wb.z; p1[7] += m1 * wb.w;
    }
#pragma unroll
    for (int j = 1; j < 64; j <<= 1) {
#pragma unroll
        for (int e = 0; e < NE; e++) {
            p0[e] += __shfl_xor(p0[e], j, 64);
            p1[e] += __shfl_xor(p1[e], j, 64);
        }
    }
    if (lane == 0) {
#pragma unroll
        for (int e = 0; e < NE; e++) {
            srw[(wv * 2) * 8 + e] = 1.0f / (1.0f + expf(-(scale * p0[e] + bias[e])));
            srw[(wv * 2 + 1) * 8 + e] = 1.0f / (1.0f + expf(-(scale * p1[e] + bias[e])));
        }
    }
    __syncthreads();
}

// ---------------------------------------------------------------------------
// Merged pre-kernel. Blocks [0,256): transpose+mean of x -> swizzled xb +
// mean1. Blocks [256,2304): permute w2 -> k-ordered bf16 wb2; blocks
// 256..287 also zero msum2/msum3; block 256 zeroes zpad (replaces memset).
// ---------------------------------------------------------------------------
__global__ __launch_bounds__(256) void pre_kernel(
    const float* __restrict__ x, unsigned short* __restrict__ xb,
    float* __restrict__ mean1,
    const float* __restrict__ w2, unsigned short* __restrict__ wb2,
    unsigned short* __restrict__ zpad,
    float* __restrict__ msum2, float* __restrict__ msum3) {
    __shared__ __align__(16) char smem[128 * 17 * 4];
    int blk = blockIdx.x, t = threadIdx.x;
    if (blk < 256) {
        float (*lt)[17] = (float(*)[17])smem;
        int b = blk >> 3, yq = blk & 7, c0 = yq * 128;
        int cr = t >> 1, half = t & 1;
        const float* src = x + ((size_t)(b * INP + c0 + cr)) * HW;
        float msum = 0.f;
        int j = t >> 4, nl = t & 15;
        for (int pg = 0; pg < 14; pg++) {
            int p0 = pg * 16 + half * 8;
            float vv[8];
            if (pg < 12) {
                float4 a = *(const float4*)(src + p0);
                float4 c = *(const float4*)(src + p0 + 4);
                vv[0] = a.x; vv[1] = a.y; vv[2] = a.z; vv[3] = a.w;
                vv[4] = c.x; vv[5] = c.y; vv[6] = c.z; vv[7] = c.w;
            } else {
#pragma unroll
                for (int i = 0; i < 8; i++) {
                    int p = p0 + i;
                    vv[i] = (p < HW) ? src[p] : 0.f;
                }
            }
#pragma unroll
            for (int i = 0; i < 8; i++) { msum += vv[i]; lt[cr][half * 8 + i] = vv[i]; }
            __syncthreads();
            unsigned short pk[8];
#pragma unroll
            for (int i = 0; i < 8; i++) pk[i] = f2bf_bits(lt[j * 8 + i][nl]);
            size_t tile = ((size_t)b * 14 + pg) * 32 + (size_t)(yq * 4 + (j >> 2));
            int lane = nl | ((j & 3) << 4);
            *(u16x8*)(xb + tile * 512 + lane * 8) = *(u16x8*)pk;
            __syncthreads();
        }
        float other = __shfl_xor(msum, 1, 64);
        if (half == 0) mean1[b * INP + c0 + cr] = (msum + other) * (1.0f / (float)HW);
    } else {
        unsigned short* lds = (unsigned short*)smem;
        int eo = blk - 256;
        // Fold the old hipMemsetAsync: zero msum2/msum3 (32*256 floats each)
        // and the first 16 B of zpad.
        if (eo < 32) {
            int idx = eo * 256 + t;
            msum2[idx] = 0.f;
            msum3[idx] = 0.f;
            if (eo == 0 && t == 0) {
                u16x8 z = {0, 0, 0, 0, 0, 0, 0, 0};
                *(u16x8*)zpad = z;
            }
        }
        const float* src = w2 + (size_t)eo * 2304 + (size_t)t * 9;
#pragma unroll
        for (int t9 = 0; t9 < 9; t9++) lds[t9 * 256 + t] = f2bf_bits(src[t9]);
        __syncthreads();
        unsigned short* dst = wb2 + (size_t)eo * 2304;
        for (int j = t; j < 288; j += 256)
            *(u16x8*)(dst + j * 8) = *(const u16x8*)(lds + j * 8);
    }
}

// ---------------------------------------------------------------------------
// Combine (contiguous-k fp32 experts, w1/w3) + fused routing.
// grid = (Mt*Kt/4), 256 threads. All 4 sample-groups handled in-block
// (g-loop) so expert weights are read ONCE instead of 4x.
// ---------------------------------------------------------------------------
__global__ __launch_bounds__(256) void combine_cont_r(
    const float* __restrict__ w, const float* __restrict__ vec,
    const float* __restrict__ rW, const float* __restrict__ rB, float scale, int C,
    unsigned short* __restrict__ cw, int S, int Mt, int Kt) {
    __shared__ float srw[64];
    int tid = threadIdx.x, wv = tid >> 6, lane = tid & 63, ml = lane & 15, k8l = lane >> 4;
    int kq = Kt >> 2;
    int mt = blockIdx.x / kq, kt = (blockIdx.x - mt * kq) * 4 + wv;
    int K = Kt * 32;
    const float* src = w + (size_t)(mt * 16 + ml) * K + kt * 32 + k8l * 8;
    float v[NE][8];
#pragma unroll
    for (int e = 0; e < NE; e++) {
        float4 a = *(const float4*)(src + (size_t)e * S);
        float4 c = *(const float4*)(src + (size_t)e * S + 4);
        v[e][0] = a.x; v[e][1] = a.y; v[e][2] = a.z; v[e][3] = a.w;
        v[e][4] = c.x; v[e][5] = c.y; v[e][6] = c.z; v[e][7] = c.w;
    }
    size_t dto = ((size_t)mt * Kt + kt) * 512 + (size_t)lane * 8;
    size_t bstr = (size_t)Mt * Kt * 512;
    for (int g = 0; g < 4; g++) {
        block_route(vec, rW, rB, scale, C, g, srw, tid);
        for (int bl = 0; bl < 8; bl++) {
            int b = g * 8 + bl;
            float acc[8];
#pragma unroll
            for (int jj = 0; jj < 8; jj++) acc[jj] = 0.f;
#pragma unroll
            for (int e = 0; e < NE; e++) {
                float r = srw[bl * NE + e];
#pragma unroll
                for (int jj = 0; jj < 8; jj++) acc[jj] += r * v[e][jj];
            }
            u16x8 o;
#pragma unroll
            for (int jj = 0; jj < 8; jj++) o[jj] = f2bf_bits(acc[jj]);
            *(u16x8*)(cw + (size_t)b * bstr + dto) = o;
        }
    }
}

// ---------------------------------------------------------------------------
// Combine w2 (k-ordered bf16 wb2) + fused routing. grid = (288); g-loop
// handles all 32 samples so wb2 is read once.
// ---------------------------------------------------------------------------
__global__ __launch_bounds__(256) void combine_w2_r(
    const unsigned short* __restrict__ wb2, const float* __restrict__ vec,
    const float* __restrict__ rW, const float* __restrict__ rB, float scale,
    unsigned short* __restrict__ cw) {
    __shared__ float srw[64];
    int tid = threadIdx.x, wv = tid >> 6, lane = tid & 63, ol = lane & 15, g4 = lane >> 4;
    int ot = blockIdx.x / 18, kt = (blockIdx.x - ot * 18) * 4 + wv;
    const unsigned short* src = wb2 + (size_t)(ot * 16 + ol) * 2304 + kt * 32 + g4 * 8;
    float v[NE][8];
#pragma unroll
    for (int e = 0; e < NE; e++) {
        u16x8 raw = *(const u16x8*)(src + (size_t)e * S2);
#pragma unroll
        for (int jj = 0; jj < 8; jj++) v[e][jj] = bf2f(raw[jj]);
    }
    size_t dto = ((size_t)ot * 72 + kt) * 512 + (size_t)lane * 8;
    for (int g = 0; g < 4; g++) {
        block_route(vec, rW, rB, scale, 256, g, srw, tid);
        for (int bl = 0; bl < 8; bl++) {
            int b = g * 8 + bl;
            float acc[8];
#pragma unroll
            for (int jj = 0; jj < 8; jj++) acc[jj] = 0.f;
#pragma unroll
            for (int e = 0; e < NE; e++) {
                float r = srw[bl * NE + e];
#pragma unroll
                for (int jj = 0; jj < 8; jj++) acc[jj] += r * v[e][jj];
            }
            u16x8 out;
#pragma unroll
            for (int jj = 0; jj < 8; jj++) out[jj] = f2bf_bits(acc[jj]);
            *(u16x8*)(cw + (size_t)b * (16 * 72 * 512) + dto) = out;
        }
    }
}

// ---------------------------------------------------------------------------
// Fused epilogue: BN + ReLU -> swizzled bf16 act + per-channel sum atomics.
// Handles nB (3 or 4) n-tiles starting at nt0.
// ---------------------------------------------------------------------------
__device__ __forceinline__ void epilogue_act(
    const f32x4* acc, int b, int mt, int nt0, int nB, int lo, int g4,
    const float* __restrict__ g, const float* __restrict__ be,
    const float* __restrict__ mu, const float* __restrict__ var,
    unsigned short* __restrict__ actout, float* __restrict__ msum) {
    int c0 = mt * 16 + g4 * 4;
    float sc[4], sh[4];
#pragma unroll
    for (int r = 0; r < 4; r++) {
        float iv = rsqrtf(var[c0 + r] + EPS) * g[c0 + r];
        sc[r] = iv;
        sh[r] = be[c0 + r] - mu[c0 + r] * iv;
    }
    float ms[4] = {0.f, 0.f, 0.f, 0.f};
    int ktc = mt >> 1;
    int lanehi = ((mt * 2 + (g4 >> 1)) & 3) << 4;
#pragma unroll
    for (int t = 0; t < 4; t++) {
        if (t >= nB) break;
        int nt = nt0 + t;
        int n = nt * 16 + lo;
        float v[4];
#pragma unroll
        for (int r = 0; r < 4; r++) {
            float val = acc[t][r] * sc[r] + sh[r];
            val = fmaxf(val, 0.f);
            if (n >= HW) val = 0.f;
            v[r] = val;
            ms[r] += val;
        }
        unsigned p01 = (unsigned)f2bf_bits(v[0]) | ((unsigned)f2bf_bits(v[1]) << 16);
        unsigned p23 = (unsigned)f2bf_bits(v[2]) | ((unsigned)f2bf_bits(v[3]) << 16);
        size_t off = (((size_t)(b * 14 + nt)) * 8 + ktc) * 512 + (size_t)(lo | lanehi) * 8 + (g4 & 1) * 4;
        *(uint2*)(actout + off) = make_uint2(p01, p23);
    }
#pragma unroll
    for (int r = 0; r < 4; r++) {
        float s = ms[r];
        s += __shfl_xor(s, 1, 64);
        s += __shfl_xor(s, 2, 64);
        s += __shfl_xor(s, 4, 64);
        s += __shfl_xor(s, 8, 64);
        if (lo == 0) atomicAdd(&msum[b * 256 + c0 + r], s);
    }
}

// ---------------------------------------------------------------------------
// Stage-1 fused GEMM, 512 threads = 8 waves, in-block split-K2.
// n-axis split in 4 chunks (4,4,3,3 tiles) -> grid (BB,4,4) = 512 blocks
// = 2 blocks/CU. LDS 32 KB.
// ---------------------------------------------------------------------------
__global__ __launch_bounds__(512) void gemm1_fused(
    const unsigned short* __restrict__ Bsw, const unsigned short* __restrict__ Asw,
    const float* __restrict__ g, const float* __restrict__ be,
    const float* __restrict__ mu, const float* __restrict__ var,
    unsigned short* __restrict__ actout, float* __restrict__ msum) {
    __shared__ __align__(16) unsigned short lAb[4][4 * 512];   // 16 KB
    __shared__ __align__(16) unsigned short lBb[4][4 * 512];   // 16 KB
    const int Kt = 32;
    int b = blockIdx.x, mh = blockIdx.y, z = blockIdx.z;
    int nt0 = (z < 3) ? z * 4 : 11;
    int nB = (z < 2) ? 4 : 3;
    int tid = threadIdx.x, wv = tid >> 6, grp = wv >> 2, wl = wv & 3;
    int lane = tid & 63, lo = lane & 15, g4 = lane >> 4;
    const unsigned short* Ab = Asw + (size_t)(b * 16 + mh * 4) * Kt * 512;
    const unsigned short* Bb = Bsw + (size_t)(b * 14 + nt0) * Kt * 512;
    f32x4 acc[4];
#pragma unroll
    for (int t = 0; t < 4; t++) acc[t] = {0.f, 0.f, 0.f, 0.f};

    auto stage = [&](int kt, unsigned short* lA, unsigned short* lB) {
        gl2lds(Ab + ((size_t)wl * Kt + kt) * 512 + lane * 8, lA + wl * 512, lane);
        if (wl < nB)
            gl2lds(Bb + ((size_t)wl * Kt + kt) * 512 + lane * 8, lB + wl * 512, lane);
    };
    auto compute = [&](const unsigned short* lA, const unsigned short* lB) {
        bf16x8 a0 = *(const bf16x8*)(lA + wl * 512 + lane * 8);
#pragma unroll
        for (int t = 0; t < 4; t++) {
            if (t >= nB) break;
            bf16x8 bt = *(const bf16x8*)(lB + t * 512 + lane * 8);
            acc[t] = __builtin_amdgcn_mfma_f32_16x16x32_bf16(a0, bt, acc[t], 0, 0, 0);
        }
    };

    stage(grp, lAb[grp], lBb[grp]);
    for (int kp = 0; kp < 16; kp++) {
        __syncthreads();
        if (kp < 15) {
            int s = 2 * kp + 2 + grp;
            stage(s, lAb[s & 3], lBb[s & 3]);
        }
        int c = (2 * kp + grp) & 3;
        compute(lAb[c], lBb[c]);
    }
    __syncthreads();
    float* red = (float*)&lBb[0][0];
    if (grp == 1) {
#pragma unroll
        for (int t = 0; t < 4; t++)
            *(f32x4*)(red + (((size_t)wl * 4 + t) * 64 + lane) * 4) = acc[t];
    }
    __syncthreads();
    if (grp == 0) {
#pragma unroll
        for (int t = 0; t < 4; t++) {
            f32x4 o = *(const f32x4*)(red + (((size_t)wl * 4 + t) * 64 + lane) * 4);
#pragma unroll
            for (int r = 0; r < 4; r++) acc[t][r] += o[r];
        }
        epilogue_act(acc, b, mh * 4 + wl, nt0, nB, lo, g4, g, be, mu, var, actout, msum);
    }
}

// ---------------------------------------------------------------------------
// Stage-2 fused GEMM (im2col gather staging), 512 threads, in-block split-K2.
// Regrid (BB,8,2): 2 m-tiles x 7 n-tiles per block -> cw2 (the 37.7 MB
// operand) is read only 2x instead of 4x; act1 gathers hit L2 (3.7 MB).
// Wave (grp, wl): msub = wl&1, nr = wl>>1 (n-tiles nr*4.., 4 or 3).
// Staging per group/k-step: wl0: A0+B0, wl1: A1+B1, wl2: B2,B3, wl3: B4-6.
// LDS 36 KB. 72 k-steps.
// ---------------------------------------------------------------------------
__global__ __launch_bounds__(512) void gemm2_fused(
    const unsigned short* __restrict__ act, const unsigned short* __restrict__ cw2,
    const unsigned short* __restrict__ zpad,
    const float* __restrict__ g, const float* __restrict__ be,
    const float* __restrict__ mu, const float* __restrict__ var,
    unsigned short* __restrict__ actout, float* __restrict__ msum) {
    __shared__ __align__(16) unsigned short lAb[4][2 * 512];   // 8 KB
    __shared__ __align__(16) unsigned short lBb[4][7 * 512];   // 28 KB
    int b = blockIdx.x, mh = blockIdx.y, nh = blockIdx.z;
    int tid = threadIdx.x, wv = tid >> 6, grp = wv >> 2, wl = wv & 3;
    int lane = tid & 63, lo = lane & 15, g4 = lane >> 4;
    const unsigned short* Ab = cw2 + (size_t)(b * 16 + mh * 2) * 72 * 512;
    const unsigned short* actb = act + (size_t)b * 14 * 8 * 512;

    // Staged-tile list per wave: wl0:{0}, wl1:{1}, wl2:{2,3}, wl3:{4,5,6}.
    int stage_cnt = (wl == 3) ? 3 : ((wl == 2) ? 2 : 1);
    int stage_b0 = (wl < 2) ? wl : ((wl == 2) ? 2 : 4);
    int spy[3], spx[3];
    bool spv[3];
#pragma unroll
    for (int j = 0; j < 3; j++) {
        int p = (nh * 7 + stage_b0 + j) * 16 + lo;
        spv[j] = p < HW;
        spy[j] = p / HH;
        spx[j] = p - (p / HH) * HH;
    }

    f32x4 acc[4];
#pragma unroll
    for (int t = 0; t < 4; t++) acc[t] = {0.f, 0.f, 0.f, 0.f};

    auto stage = [&](int kt, unsigned short* lA, unsigned short* lB) {
        if (wl < 2)
            gl2lds(Ab + ((size_t)wl * 72 + kt) * 512 + lane * 8, lA + wl * 512, lane);
        int t9 = kt >> 3;
        int dy = t9 / 3 - 1, dx = t9 - (t9 / 3) * 3 - 1;
        int itile = kt & 7;
#pragma unroll
        for (int j = 0; j < 3; j++) {
            if (j >= stage_cnt) break;
            int sy = spy[j] + dy, sx = spx[j] + dx;
            bool ok = spv[j] && sy >= 0 && sy < HH && sx >= 0 && sx < HH;
            int ns = sy * HH + sx;
            const unsigned short* gp = ok
                ? actb + ((size_t)(ns >> 4) * 8 + itile) * 512 + (size_t)((ns & 15) | (g4 << 4)) * 8
                : zpad;
            gl2lds(gp, lB + (stage_b0 + j) * 512, lane);
        }
    };
    auto compute = [&](const unsigned short* lA, const unsigned short* lB) {
        int msub = wl & 1, nr = wl >> 1;
        int ntl = nr ? 3 : 4;
        int bt0 = nr * 4;
        bf16x8 a0 = *(const bf16x8*)(lA + msub * 512 + lane * 8);
#pragma unroll
        for (int t = 0; t < 4; t++) {
            if (t >= ntl) break;
            bf16x8 bt = *(const bf16x8*)(lB + (bt0 + t) * 512 + lane * 8);
            acc[t] = __builtin_amdgcn_mfma_f32_16x16x32_bf16(a0, bt, acc[t], 0, 0, 0);
        }
    };

    stage(grp, lAb[grp], lBb[grp]);
    for (int kp = 0; kp < 36; kp++) {
        __syncthreads();
        if (kp < 35) {
            int s = 2 * kp + 2 + grp;
            stage(s, lAb[s & 3], lBb[s & 3]);
        }
        int c = (2 * kp + grp) & 3;
        compute(lAb[c], lBb[c]);
    }
    __syncthreads();
    float* red = (float*)&lBb[0][0];   // 16 KB used
    if (grp == 1) {
#pragma unroll
        for (int t = 0; t < 4; t++)
            *(f32x4*)(red + (((size_t)wl * 4 + t) * 64 + lane) * 4) = acc[t];
    }
    __syncthreads();
    if (grp == 0) {
        int msub = wl & 1, nr = wl >> 1;
        int ntl = nr ? 3 : 4;
#pragma unroll
        for (int t = 0; t < 4; t++) {
            f32x4 o = *(const f32x4*)(red + (((size_t)wl * 4 + t) * 64 + lane) * 4);
#pragma unroll
            for (int r = 0; r < 4; r++) acc[t][r] += o[r];
        }
        epilogue_act(acc, b, mh * 2 + msub, nh * 7 + nr * 4, ntl, lo, g4,
                     g, be, mu, var, actout, msum);
    }
}

// ---------------------------------------------------------------------------
// Stage-3 GEMM, 512 threads, in-block split-K2, fused BN + bf16 residual
// (from swizzled xb) + ReLU -> fp32 NCHW. grid (BB, 16) = 512 blocks
// (2 blocks/CU at 60 KB LDS). K=256 (8 steps).
// ---------------------------------------------------------------------------
__global__ __launch_bounds__(512) void gemm3_fused(
    const unsigned short* __restrict__ Bsw, const unsigned short* __restrict__ Asw,
    const float* __restrict__ g, const float* __restrict__ be,
    const float* __restrict__ mu, const float* __restrict__ var,
    const unsigned short* __restrict__ xb, float* __restrict__ out) {
    __shared__ __align__(16) unsigned short lAb[4][8 * 512];
    __shared__ __align__(16) unsigned short lBb[4][7 * 512];
    int b = blockIdx.x, y = blockIdx.y, mh = y >> 1, nh = y & 1;
    int tid = threadIdx.x, wv = tid >> 6, grp = wv >> 2, wl = wv & 3;
    int lane = tid & 63, lo = lane & 15, g4 = lane >> 4;
    const unsigned short* Ab = Asw + (size_t)(b * 64 + mh * 8) * 8 * 512;
    const unsigned short* Bb = Bsw + (size_t)(b * 14 + nh * 7) * 8 * 512;
    f32x4 acc0[7], acc1[7];
#pragma unroll
    for (int t = 0; t < 7; t++) { acc0[t] = {0.f, 0.f, 0.f, 0.f}; acc1[t] = {0.f, 0.f, 0.f, 0.f}; }

    auto stage = [&](int kt, unsigned short* lA, unsigned short* lB) {
        gl2lds(Ab + ((size_t)wl * 8 + kt) * 512 + lane * 8, lA + wl * 512, lane);
        gl2lds(Ab + ((size_t)(wl + 4) * 8 + kt) * 512 + lane * 8, lA + (wl + 4) * 512, lane);
        gl2lds(Bb + ((size_t)wl * 8 + kt) * 512 + lane * 8, lB + wl * 512, lane);
        if (wl < 3)
            gl2lds(Bb + ((size_t)(4 + wl) * 8 + kt) * 512 + lane * 8, lB + (4 + wl) * 512, lane);
    };
    auto compute = [&](const unsigned short* lA, const unsigned short* lB) {
        bf16x8 a0 = *(const bf16x8*)(lA + wl * 512 + lane * 8);
        bf16x8 a1 = *(const bf16x8*)(lA + (wl + 4) * 512 + lane * 8);
#pragma unroll
        for (int t = 0; t < 7; t++) {
            bf16x8 bt = *(const bf16x8*)(lB + t * 512 + lane * 8);
            acc0[t] = __builtin_amdgcn_mfma_f32_16x16x32_bf16(a0, bt, acc0[t], 0, 0, 0);
            acc1[t] = __builtin_amdgcn_mfma_f32_16x16x32_bf16(a1, bt, acc1[t], 0, 0, 0);
        }
    };

    stage(grp, lAb[grp], lBb[grp]);
    for (int kp = 0; kp < 4; kp++) {
        __syncthreads();
        if (kp < 3) {
            int s = 2 * kp + 2 + grp;
            stage(s, lAb[s & 3], lBb[s & 3]);
        }
        int c = (2 * kp + grp) & 3;
        compute(lAb[c], lBb[c]);
    }
    __syncthreads();
    float* red = (float*)&lBb[0][0];
    if (grp == 1) {
#pragma unroll
        for (int t = 0; t < 7; t++)
            *(f32x4*)(red + (((size_t)wl * 7 + t) * 64 + lane) * 4) = acc0[t];
    }
    __syncthreads();
    if (grp == 0) {
#pragma unroll
        for (int t = 0; t < 7; t++) {
            f32x4 o = *(const f32x4*)(red + (((size_t)wl * 7 + t) * 64 + lane) * 4);
#pragma unroll
            for (int r = 0; r < 4; r++) acc0[t][r] += o[r];
        }
    }
    __syncthreads();
    if (grp == 1) {
#pragma unroll
        for (int t = 0; t < 7; t++)
            *(f32x4*)(red + (((size_t)wl * 7 + t) * 64 + lane) * 4) = acc1[t];
    }
    __syncthreads();
    if (grp != 0) return;
#pragma unroll
    for (int t = 0; t < 7; t++) {
        f32x4 o = *(const f32x4*)(red + (((size_t)wl * 7 + t) * 64 + lane) * 4);
#pragma unroll
        for (int r = 0; r < 4; r++) acc1[t][r] += o[r];
    }

#pragma unroll
    for (int a = 0; a < 2; a++) {
        int mt = mh * 8 + wl + 4 * a;
        int c0 = mt * 16 + g4 * 4;
        float sc[4], sh[4];
#pragma unroll
        for (int r = 0; r < 4; r++) {
            float iv = rsqrtf(var[c0 + r] + EPS) * g[c0 + r];
            sc[r] = iv;
            sh[r] = be[c0 + r] - mu[c0 + r] * iv;
        }
        int ktc = mt >> 1;
        int lanehi = ((mt * 2 + (g4 >> 1)) & 3) << 4;
#pragma unroll
        for (int t = 0; t < 7; t++) {
            int nt = nh * 7 + t;
            int n = nt * 16 + lo;
            if (n >= HW) continue;
            const unsigned short* xr = xb + (((size_t)(b * 14 + nt)) * 32 + ktc) * 512
                                       + (size_t)(lo | lanehi) * 8 + (g4 & 1) * 4;
            uint2 rv = *(const uint2*)xr;
            float res[4] = {bf2f((unsigned short)(rv.x & 0xffff)),
                            bf2f((unsigned short)(rv.x >> 16)),
                            bf2f((unsigned short)(rv.y & 0xffff)),
                            bf2f((unsigned short)(rv.y >> 16))};
            f32x4 av = a ? acc1[t] : acc0[t];
#pragma unroll
            for (int r = 0; r < 4; r++) {
                size_t oidx = ((size_t)(b * OUTP + c0 + r)) * HW + n;
                float val = av[r] * sc[r] + sh[r] + res[r];
                out[oidx] = fmaxf(val, 0.f);
            }
        }
    }
}

// ---------------------------------------------------------------------------
extern "C" void kernel_launch(void* const* d_in, const int* in_sizes, int n_in,
                              void* d_out, int out_size, void* d_ws, size_t ws_size,
                              hipStream_t stream) {
    const float* x    = (const float*)d_in[0];
    const float* w1   = (const float*)d_in[1];
    const float* w2   = (const float*)d_in[2];
    const float* w3   = (const float*)d_in[3];
    const float* r1_w = (const float*)d_in[4];
    const float* r1_b = (const float*)d_in[5];
    const float* r2_w = (const float*)d_in[6];
    const float* r2_b = (const float*)d_in[7];
    const float* r3_w = (const float*)d_in[8];
    const float* r3_b = (const float*)d_in[9];
    const float* bn1_g = (const float*)d_in[10];
    const float* bn1_b = (const float*)d_in[11];
    const float* bn1_m = (const float*)d_in[12];
    const float* bn1_v = (const float*)d_in[13];
    const float* bn2_g = (const float*)d_in[14];
    const float* bn2_b = (const float*)d_in[15];
    const float* bn2_m = (const float*)d_in[16];
    const float* bn2_v = (const float*)d_in[17];
    const float* bn3_g = (const float*)d_in[18];
    const float* bn3_b = (const float*)d_in[19];
    const float* bn3_m = (const float*)d_in[20];
    const float* bn3_v = (const float*)d_in[21];
    float* out = (float*)d_out;

    // Workspace (~86.4 MB). cwX slot time-shared: cw1 (stage 1) then cw3
    // (stage 3; cw1 dead after gemm1). xb persists to gemm3 (bf16 residual).
    char* ws = (char*)d_ws;
    size_t off = 0;
    float* mean1 = (float*)(ws + off); off += (size_t)BB * INP * 4;
    float* msum2 = (float*)(ws + off); off += (size_t)BB * 256 * 4;
    float* msum3 = (float*)(ws + off); off += (size_t)BB * 256 * 4;
    unsigned short* zpad = (unsigned short*)(ws + off); off += 256;
    off = (off + 255) & ~(size_t)255;
    unsigned short* act1 = (unsigned short*)(ws + off); off += (size_t)BB * 14 * 8 * 512 * 2;  // 3.67 MB
    unsigned short* act2 = (unsigned short*)(ws + off); off += (size_t)BB * 14 * 8 * 512 * 2;  // 3.67 MB
    unsigned short* cw2 = (unsigned short*)(ws + off); off += (size_t)BB * 16 * 72 * 512 * 2;  // 37.75 MB
    unsigned short* xb  = (unsigned short*)(ws + off); off += (size_t)BB * 14 * 32 * 512 * 2;  // 14.68 MB
    unsigned short* wb2 = (unsigned short*)(ws + off); off += (size_t)S2 * NE * 2;             // 9.44 MB
    unsigned short* cwX = (unsigned short*)(ws + off); off += (size_t)BB * S1 * 2;             // 16.78 MB
    unsigned short* cw1 = cwX;
    unsigned short* cw3 = cwX;
    (void)ws_size;

    // Pre: transpose+mean of x (blocks 0-255) || permute w2 + zero
    // msum2/msum3/zpad (blocks 256-2303). Memset dispatch eliminated.
    pre_kernel<<<2304, 256, 0, stream>>>(x, xb, mean1, w2, wb2, zpad, msum2, msum3);

    // Stage 1: 1x1 conv 1024->256
    combine_cont_r<<<128, 256, 0, stream>>>(w1, mean1, r1_w, r1_b, 1.0f, INP,
                                            cw1, S1, 16, 32);
    gemm1_fused<<<dim3(BB, 4, 4), 512, 0, stream>>>(xb, cw1, bn1_g, bn1_b, bn1_m, bn1_v,
                                                    act1, msum2);

    // Stage 2: 3x3 conv 256->256
    combine_w2_r<<<288, 256, 0, stream>>>(wb2, msum2, r2_w, r2_b,
                                          1.0f / (float)HW, cw2);
    gemm2_fused<<<dim3(BB, 8, 2), 512, 0, stream>>>(act1, cw2, zpad, bn2_g, bn2_b,
                                                    bn2_m, bn2_v, act2, msum3);

    // Stage 3: 1x1 conv 256->1024 + residual
    combine_cont_r<<<128, 256, 0, stream>>>(w3, msum3, r3_w, r3_b,
                                            1.0f / (float)HW, WIDTH,
                                            cw3, S3, 64, 8);
    gemm3_fused<<<dim3(BB, 16), 512, 0, stream>>>(act2, cw3, bn3_g, bn3_b, bn3_m, bn3_v,
                                                  xb, out);
}

// Round 4
// 243.858 us; speedup vs baseline: 1.1914x; 1.1914x over previous
//
#include <hip/hip_runtime.h>
#include <hip/hip_bf16.h>

#define BB 32
#define INP 1024
#define WIDTH 256
#define OUTP 1024
#define NE 8
#define HW 196
#define HH 14
#define EPS 1e-5f

#define S1 (WIDTH * INP)        // 262144
#define S2 (WIDTH * WIDTH * 9)  // 589824
#define S3 (OUTP * WIDTH)       // 262144

typedef __attribute__((ext_vector_type(8))) short bf16x8;
typedef __attribute__((ext_vector_type(4))) float f32x4;
typedef __attribute__((ext_vector_type(8))) unsigned short u16x8;

// Swizzled operand layout: tile = 16 rows x 32 k = 512 bf16 = 1 KB.
// Element (r,k) at lane*8 + (k&7), lane = (r&15) | (((k>>3)&3)<<4).

__device__ __forceinline__ unsigned short f2bf_bits(float f) {
    unsigned u = __float_as_uint(f);
    u += 0x7FFFu + ((u >> 16) & 1u);   // RNE
    return (unsigned short)(u >> 16);
}
__device__ __forceinline__ float bf2f(unsigned short h) {
    return __uint_as_float((unsigned)h << 16);
}

#if defined(__has_builtin)
#if __has_builtin(__builtin_amdgcn_global_load_lds)
#define HAVE_GLL 1
#endif
#endif
__device__ __forceinline__ void gl2lds(const unsigned short* g, unsigned short* l,
                                       int lane) {
#ifdef HAVE_GLL
    __builtin_amdgcn_global_load_lds(
        (const __attribute__((address_space(1))) unsigned int*)(const void*)g,
        (__attribute__((address_space(3))) unsigned int*)(void*)l, 16, 0, 0);
#else
    *(u16x8*)(l + lane * 8) = *(const u16x8*)g;
#endif
}

// ---------------------------------------------------------------------------
// In-block routing (8-sample group g): srw[s*8+e] = sigmoid(scale*(v@W)+b).
// Called once per block (g = blockIdx.y). Occupancy > L3-traffic savings:
// do NOT fold sample-groups into a block loop (round-3 regression, 4.6% occ).
// ---------------------------------------------------------------------------
__device__ __forceinline__ void block_route(
    const float* __restrict__ vec, const float* __restrict__ W,
    const float* __restrict__ bias, float scale, int C, int g,
    float* srw, int tid) {
    int wv = tid >> 6, lane = tid & 63;
    float p0[NE], p1[NE];
#pragma unroll
    for (int e = 0; e < NE; e++) { p0[e] = 0.f; p1[e] = 0.f; }
    const float* v0 = vec + (size_t)(g * 8 + wv * 2) * C;
    const float* v1 = v0 + C;
    for (int c = lane; c < C; c += 64) {
        float4 wa = *(const float4*)(W + c * 8);
        float4 wb = *(const float4*)(W + c * 8 + 4);
        float m0 = v0[c], m1 = v1[c];
        p0[0] += m0 * wa.x; p0[1] += m0 * wa.y; p0[2] += m0 * wa.z; p0[3] += m0 * wa.w;
        p0[4] += m0 * wb.x; p0[5] += m0 * wb.y; p0[6] += m0 * wb.z; p0[7] += m0 * wb.w;
        p1[0] += m1 * wa.x; p1[1] += m1 * wa.y; p1[2] += m1 * wa.z; p1[3] += m1 * wa.w;
        p1[4] += m1 * wb.x; p1[5] += m1 * wb.y; p1[6] += m1 * wb.z; p1[7] += m1 * wb.w;
    }
#pragma unroll
    for (int j = 1; j < 64; j <<= 1) {
#pragma unroll
        for (int e = 0; e < NE; e++) {
            p0[e] += __shfl_xor(p0[e], j, 64);
            p1[e] += __shfl_xor(p1[e], j, 64);
        }
    }
    if (lane == 0) {
#pragma unroll
        for (int e = 0; e < NE; e++) {
            srw[(wv * 2) * 8 + e] = 1.0f / (1.0f + expf(-(scale * p0[e] + bias[e])));
            srw[(wv * 2 + 1) * 8 + e] = 1.0f / (1.0f + expf(-(scale * p1[e] + bias[e])));
        }
    }
    __syncthreads();
}

// ---------------------------------------------------------------------------
// Merged pre-kernel. Blocks [0,256): transpose+mean of x -> swizzled xb +
// mean1. Blocks [256,2304): permute w2 -> k-ordered bf16 wb2; blocks
// 256..287 also zero msum2/msum3; block 256 zeroes zpad (replaces memset).
// ---------------------------------------------------------------------------
__global__ __launch_bounds__(256) void pre_kernel(
    const float* __restrict__ x, unsigned short* __restrict__ xb,
    float* __restrict__ mean1,
    const float* __restrict__ w2, unsigned short* __restrict__ wb2,
    unsigned short* __restrict__ zpad,
    float* __restrict__ msum2, float* __restrict__ msum3) {
    __shared__ __align__(16) char smem[128 * 17 * 4];
    int blk = blockIdx.x, t = threadIdx.x;
    if (blk < 256) {
        float (*lt)[17] = (float(*)[17])smem;
        int b = blk >> 3, yq = blk & 7, c0 = yq * 128;
        int cr = t >> 1, half = t & 1;
        const float* src = x + ((size_t)(b * INP + c0 + cr)) * HW;
        float msum = 0.f;
        int j = t >> 4, nl = t & 15;
        for (int pg = 0; pg < 14; pg++) {
            int p0 = pg * 16 + half * 8;
            float vv[8];
            if (pg < 12) {
                float4 a = *(const float4*)(src + p0);
                float4 c = *(const float4*)(src + p0 + 4);
                vv[0] = a.x; vv[1] = a.y; vv[2] = a.z; vv[3] = a.w;
                vv[4] = c.x; vv[5] = c.y; vv[6] = c.z; vv[7] = c.w;
            } else {
#pragma unroll
                for (int i = 0; i < 8; i++) {
                    int p = p0 + i;
                    vv[i] = (p < HW) ? src[p] : 0.f;
                }
            }
#pragma unroll
            for (int i = 0; i < 8; i++) { msum += vv[i]; lt[cr][half * 8 + i] = vv[i]; }
            __syncthreads();
            unsigned short pk[8];
#pragma unroll
            for (int i = 0; i < 8; i++) pk[i] = f2bf_bits(lt[j * 8 + i][nl]);
            size_t tile = ((size_t)b * 14 + pg) * 32 + (size_t)(yq * 4 + (j >> 2));
            int lane = nl | ((j & 3) << 4);
            *(u16x8*)(xb + tile * 512 + lane * 8) = *(u16x8*)pk;
            __syncthreads();
        }
        float other = __shfl_xor(msum, 1, 64);
        if (half == 0) mean1[b * INP + c0 + cr] = (msum + other) * (1.0f / (float)HW);
    } else {
        unsigned short* lds = (unsigned short*)smem;
        int eo = blk - 256;
        // Fold the old hipMemsetAsync: zero msum2/msum3 (32*256 floats each)
        // and the first 16 B of zpad.
        if (eo < 32) {
            int idx = eo * 256 + t;
            msum2[idx] = 0.f;
            msum3[idx] = 0.f;
            if (eo == 0 && t == 0) {
                u16x8 z = {0, 0, 0, 0, 0, 0, 0, 0};
                *(u16x8*)zpad = z;
            }
        }
        const float* src = w2 + (size_t)eo * 2304 + (size_t)t * 9;
#pragma unroll
        for (int t9 = 0; t9 < 9; t9++) lds[t9 * 256 + t] = f2bf_bits(src[t9]);
        __syncthreads();
        unsigned short* dst = wb2 + (size_t)eo * 2304;
        for (int j = t; j < 288; j += 256)
            *(u16x8*)(dst + j * 8) = *(const u16x8*)(lds + j * 8);
    }
}

// ---------------------------------------------------------------------------
// Combine (contiguous-k fp32 experts, w1/w3) + fused routing.
// grid = (Mt*Kt/4, 4 sample groups), 256 threads. Weight re-reads across
// the 4 y-blocks are L3-absorbed (measured FETCH ~5 MB) — keep the grid fat.
// ---------------------------------------------------------------------------
__global__ __launch_bounds__(256) void combine_cont_r(
    const float* __restrict__ w, const float* __restrict__ vec,
    const float* __restrict__ rW, const float* __restrict__ rB, float scale, int C,
    unsigned short* __restrict__ cw, int S, int Mt, int Kt) {
    __shared__ float srw[64];
    int tid = threadIdx.x, wv = tid >> 6, lane = tid & 63, ml = lane & 15, k8l = lane >> 4;
    int g = blockIdx.y;
    block_route(vec, rW, rB, scale, C, g, srw, tid);
    int kq = Kt >> 2;
    int mt = blockIdx.x / kq, kt = (blockIdx.x - mt * kq) * 4 + wv;
    int K = Kt * 32;
    const float* src = w + (size_t)(mt * 16 + ml) * K + kt * 32 + k8l * 8;
    float v[NE][8];
#pragma unroll
    for (int e = 0; e < NE; e++) {
        float4 a = *(const float4*)(src + (size_t)e * S);
        float4 c = *(const float4*)(src + (size_t)e * S + 4);
        v[e][0] = a.x; v[e][1] = a.y; v[e][2] = a.z; v[e][3] = a.w;
        v[e][4] = c.x; v[e][5] = c.y; v[e][6] = c.z; v[e][7] = c.w;
    }
    size_t dto = ((size_t)mt * Kt + kt) * 512 + (size_t)lane * 8;
    size_t bstr = (size_t)Mt * Kt * 512;
    for (int bl = 0; bl < 8; bl++) {
        int b = g * 8 + bl;
        float acc[8];
#pragma unroll
        for (int jj = 0; jj < 8; jj++) acc[jj] = 0.f;
#pragma unroll
        for (int e = 0; e < NE; e++) {
            float r = srw[bl * NE + e];
#pragma unroll
            for (int jj = 0; jj < 8; jj++) acc[jj] += r * v[e][jj];
        }
        u16x8 o;
#pragma unroll
        for (int jj = 0; jj < 8; jj++) o[jj] = f2bf_bits(acc[jj]);
        *(u16x8*)(cw + (size_t)b * bstr + dto) = o;
    }
}

// ---------------------------------------------------------------------------
// Combine w2 (k-ordered bf16 wb2) + fused routing. grid = (288, 4 groups).
// ---------------------------------------------------------------------------
__global__ __launch_bounds__(256) void combine_w2_r(
    const unsigned short* __restrict__ wb2, const float* __restrict__ vec,
    const float* __restrict__ rW, const float* __restrict__ rB, float scale,
    unsigned short* __restrict__ cw) {
    __shared__ float srw[64];
    int tid = threadIdx.x, wv = tid >> 6, lane = tid & 63, ol = lane & 15, g4 = lane >> 4;
    int g = blockIdx.y;
    block_route(vec, rW, rB, scale, 256, g, srw, tid);
    int ot = blockIdx.x / 18, kt = (blockIdx.x - ot * 18) * 4 + wv;
    const unsigned short* src = wb2 + (size_t)(ot * 16 + ol) * 2304 + kt * 32 + g4 * 8;
    float v[NE][8];
#pragma unroll
    for (int e = 0; e < NE; e++) {
        u16x8 raw = *(const u16x8*)(src + (size_t)e * S2);
#pragma unroll
        for (int jj = 0; jj < 8; jj++) v[e][jj] = bf2f(raw[jj]);
    }
    size_t dto = ((size_t)ot * 72 + kt) * 512 + (size_t)lane * 8;
    for (int bl = 0; bl < 8; bl++) {
        int b = g * 8 + bl;
        float acc[8];
#pragma unroll
        for (int jj = 0; jj < 8; jj++) acc[jj] = 0.f;
#pragma unroll
        for (int e = 0; e < NE; e++) {
            float r = srw[bl * NE + e];
#pragma unroll
            for (int jj = 0; jj < 8; jj++) acc[jj] += r * v[e][jj];
        }
        u16x8 out;
#pragma unroll
        for (int jj = 0; jj < 8; jj++) out[jj] = f2bf_bits(acc[jj]);
        *(u16x8*)(cw + (size_t)b * (16 * 72 * 512) + dto) = out;
    }
}

// ---------------------------------------------------------------------------
// Fused epilogue: BN + ReLU -> swizzled bf16 act + per-channel sum atomics.
// Handles nB (3 or 4) n-tiles starting at nt0.
// ---------------------------------------------------------------------------
__device__ __forceinline__ void epilogue_act(
    const f32x4* acc, int b, int mt, int nt0, int nB, int lo, int g4,
    const float* __restrict__ g, const float* __restrict__ be,
    const float* __restrict__ mu, const float* __restrict__ var,
    unsigned short* __restrict__ actout, float* __restrict__ msum) {
    int c0 = mt * 16 + g4 * 4;
    float sc[4], sh[4];
#pragma unroll
    for (int r = 0; r < 4; r++) {
        float iv = rsqrtf(var[c0 + r] + EPS) * g[c0 + r];
        sc[r] = iv;
        sh[r] = be[c0 + r] - mu[c0 + r] * iv;
    }
    float ms[4] = {0.f, 0.f, 0.f, 0.f};
    int ktc = mt >> 1;
    int lanehi = ((mt * 2 + (g4 >> 1)) & 3) << 4;
#pragma unroll
    for (int t = 0; t < 4; t++) {
        if (t >= nB) break;
        int nt = nt0 + t;
        int n = nt * 16 + lo;
        float v[4];
#pragma unroll
        for (int r = 0; r < 4; r++) {
            float val = acc[t][r] * sc[r] + sh[r];
            val = fmaxf(val, 0.f);
            if (n >= HW) val = 0.f;
            v[r] = val;
            ms[r] += val;
        }
        unsigned p01 = (unsigned)f2bf_bits(v[0]) | ((unsigned)f2bf_bits(v[1]) << 16);
        unsigned p23 = (unsigned)f2bf_bits(v[2]) | ((unsigned)f2bf_bits(v[3]) << 16);
        size_t off = (((size_t)(b * 14 + nt)) * 8 + ktc) * 512 + (size_t)(lo | lanehi) * 8 + (g4 & 1) * 4;
        *(uint2*)(actout + off) = make_uint2(p01, p23);
    }
#pragma unroll
    for (int r = 0; r < 4; r++) {
        float s = ms[r];
        s += __shfl_xor(s, 1, 64);
        s += __shfl_xor(s, 2, 64);
        s += __shfl_xor(s, 4, 64);
        s += __shfl_xor(s, 8, 64);
        if (lo == 0) atomicAdd(&msum[b * 256 + c0 + r], s);
    }
}

// ---------------------------------------------------------------------------
// Stage-1 fused GEMM, 512 threads = 8 waves, in-block split-K2.
// n-axis split in 4 chunks (4,4,3,3 tiles) -> grid (BB,4,4) = 512 blocks
// = 2 blocks/CU. LDS 32 KB.
// ---------------------------------------------------------------------------
__global__ __launch_bounds__(512) void gemm1_fused(
    const unsigned short* __restrict__ Bsw, const unsigned short* __restrict__ Asw,
    const float* __restrict__ g, const float* __restrict__ be,
    const float* __restrict__ mu, const float* __restrict__ var,
    unsigned short* __restrict__ actout, float* __restrict__ msum) {
    __shared__ __align__(16) unsigned short lAb[4][4 * 512];   // 16 KB
    __shared__ __align__(16) unsigned short lBb[4][4 * 512];   // 16 KB
    const int Kt = 32;
    int b = blockIdx.x, mh = blockIdx.y, z = blockIdx.z;
    int nt0 = (z < 3) ? z * 4 : 11;
    int nB = (z < 2) ? 4 : 3;
    int tid = threadIdx.x, wv = tid >> 6, grp = wv >> 2, wl = wv & 3;
    int lane = tid & 63, lo = lane & 15, g4 = lane >> 4;
    const unsigned short* Ab = Asw + (size_t)(b * 16 + mh * 4) * Kt * 512;
    const unsigned short* Bb = Bsw + (size_t)(b * 14 + nt0) * Kt * 512;
    f32x4 acc[4];
#pragma unroll
    for (int t = 0; t < 4; t++) acc[t] = {0.f, 0.f, 0.f, 0.f};

    auto stage = [&](int kt, unsigned short* lA, unsigned short* lB) {
        gl2lds(Ab + ((size_t)wl * Kt + kt) * 512 + lane * 8, lA + wl * 512, lane);
        if (wl < nB)
            gl2lds(Bb + ((size_t)wl * Kt + kt) * 512 + lane * 8, lB + wl * 512, lane);
    };
    auto compute = [&](const unsigned short* lA, const unsigned short* lB) {
        bf16x8 a0 = *(const bf16x8*)(lA + wl * 512 + lane * 8);
#pragma unroll
        for (int t = 0; t < 4; t++) {
            if (t >= nB) break;
            bf16x8 bt = *(const bf16x8*)(lB + t * 512 + lane * 8);
            acc[t] = __builtin_amdgcn_mfma_f32_16x16x32_bf16(a0, bt, acc[t], 0, 0, 0);
        }
    };

    stage(grp, lAb[grp], lBb[grp]);
    for (int kp = 0; kp < 16; kp++) {
        __syncthreads();
        if (kp < 15) {
            int s = 2 * kp + 2 + grp;
            stage(s, lAb[s & 3], lBb[s & 3]);
        }
        int c = (2 * kp + grp) & 3;
        compute(lAb[c], lBb[c]);
    }
    __syncthreads();
    float* red = (float*)&lBb[0][0];
    if (grp == 1) {
#pragma unroll
        for (int t = 0; t < 4; t++)
            *(f32x4*)(red + (((size_t)wl * 4 + t) * 64 + lane) * 4) = acc[t];
    }
    __syncthreads();
    if (grp == 0) {
#pragma unroll
        for (int t = 0; t < 4; t++) {
            f32x4 o = *(const f32x4*)(red + (((size_t)wl * 4 + t) * 64 + lane) * 4);
#pragma unroll
            for (int r = 0; r < 4; r++) acc[t][r] += o[r];
        }
        epilogue_act(acc, b, mh * 4 + wl, nt0, nB, lo, g4, g, be, mu, var, actout, msum);
    }
}

// ---------------------------------------------------------------------------
// Stage-2 fused GEMM (im2col gather staging), 512 threads, in-block split-K2.
// Regrid (BB,8,2): 2 m-tiles x 7 n-tiles per block -> cw2 (the 37.7 MB
// operand) is read only 2x instead of 4x; act1 gathers hit L2 (3.7 MB).
// Wave (grp, wl): msub = wl&1, nr = wl>>1 (n-tiles nr*4.., 4 or 3).
// Staging per group/k-step: wl0: A0+B0, wl1: A1+B1, wl2: B2,B3, wl3: B4-6.
// LDS 36 KB. 72 k-steps.
// ---------------------------------------------------------------------------
__global__ __launch_bounds__(512) void gemm2_fused(
    const unsigned short* __restrict__ act, const unsigned short* __restrict__ cw2,
    const unsigned short* __restrict__ zpad,
    const float* __restrict__ g, const float* __restrict__ be,
    const float* __restrict__ mu, const float* __restrict__ var,
    unsigned short* __restrict__ actout, float* __restrict__ msum) {
    __shared__ __align__(16) unsigned short lAb[4][2 * 512];   // 8 KB
    __shared__ __align__(16) unsigned short lBb[4][7 * 512];   // 28 KB
    int b = blockIdx.x, mh = blockIdx.y, nh = blockIdx.z;
    int tid = threadIdx.x, wv = tid >> 6, grp = wv >> 2, wl = wv & 3;
    int lane = tid & 63, lo = lane & 15, g4 = lane >> 4;
    const unsigned short* Ab = cw2 + (size_t)(b * 16 + mh * 2) * 72 * 512;
    const unsigned short* actb = act + (size_t)b * 14 * 8 * 512;

    // Staged-tile list per wave: wl0:{0}, wl1:{1}, wl2:{2,3}, wl3:{4,5,6}.
    int stage_cnt = (wl == 3) ? 3 : ((wl == 2) ? 2 : 1);
    int stage_b0 = (wl < 2) ? wl : ((wl == 2) ? 2 : 4);
    int spy[3], spx[3];
    bool spv[3];
#pragma unroll
    for (int j = 0; j < 3; j++) {
        int p = (nh * 7 + stage_b0 + j) * 16 + lo;
        spv[j] = p < HW;
        spy[j] = p / HH;
        spx[j] = p - (p / HH) * HH;
    }

    f32x4 acc[4];
#pragma unroll
    for (int t = 0; t < 4; t++) acc[t] = {0.f, 0.f, 0.f, 0.f};

    auto stage = [&](int kt, unsigned short* lA, unsigned short* lB) {
        if (wl < 2)
            gl2lds(Ab + ((size_t)wl * 72 + kt) * 512 + lane * 8, lA + wl * 512, lane);
        int t9 = kt >> 3;
        int dy = t9 / 3 - 1, dx = t9 - (t9 / 3) * 3 - 1;
        int itile = kt & 7;
#pragma unroll
        for (int j = 0; j < 3; j++) {
            if (j >= stage_cnt) break;
            int sy = spy[j] + dy, sx = spx[j] + dx;
            bool ok = spv[j] && sy >= 0 && sy < HH && sx >= 0 && sx < HH;
            int ns = sy * HH + sx;
            const unsigned short* gp = ok
                ? actb + ((size_t)(ns >> 4) * 8 + itile) * 512 + (size_t)((ns & 15) | (g4 << 4)) * 8
                : zpad;
            gl2lds(gp, lB + (stage_b0 + j) * 512, lane);
        }
    };
    auto compute = [&](const unsigned short* lA, const unsigned short* lB) {
        int msub = wl & 1, nr = wl >> 1;
        int ntl = nr ? 3 : 4;
        int bt0 = nr * 4;
        bf16x8 a0 = *(const bf16x8*)(lA + msub * 512 + lane * 8);
#pragma unroll
        for (int t = 0; t < 4; t++) {
            if (t >= ntl) break;
            bf16x8 bt = *(const bf16x8*)(lB + (bt0 + t) * 512 + lane * 8);
            acc[t] = __builtin_amdgcn_mfma_f32_16x16x32_bf16(a0, bt, acc[t], 0, 0, 0);
        }
    };

    stage(grp, lAb[grp], lBb[grp]);
    for (int kp = 0; kp < 36; kp++) {
        __syncthreads();
        if (kp < 35) {
            int s = 2 * kp + 2 + grp;
            stage(s, lAb[s & 3], lBb[s & 3]);
        }
        int c = (2 * kp + grp) & 3;
        compute(lAb[c], lBb[c]);
    }
    __syncthreads();
    float* red = (float*)&lBb[0][0];   // 16 KB used
    if (grp == 1) {
#pragma unroll
        for (int t = 0; t < 4; t++)
            *(f32x4*)(red + (((size_t)wl * 4 + t) * 64 + lane) * 4) = acc[t];
    }
    __syncthreads();
    if (grp == 0) {
        int msub = wl & 1, nr = wl >> 1;
        int ntl = nr ? 3 : 4;
#pragma unroll
        for (int t = 0; t < 4; t++) {
            f32x4 o = *(const f32x4*)(red + (((size_t)wl * 4 + t) * 64 + lane) * 4);
#pragma unroll
            for (int r = 0; r < 4; r++) acc[t][r] += o[r];
        }
        epilogue_act(acc, b, mh * 2 + msub, nh * 7 + nr * 4, ntl, lo, g4,
                     g, be, mu, var, actout, msum);
    }
}

// ---------------------------------------------------------------------------
// Stage-3 GEMM, 512 threads, in-block split-K2, fused BN + bf16 residual
// (from swizzled xb) + ReLU -> fp32 NCHW. grid (BB, 16) = 512 blocks
// (2 blocks/CU at 60 KB LDS). K=256 (8 steps).
// ---------------------------------------------------------------------------
__global__ __launch_bounds__(512) void gemm3_fused(
    const unsigned short* __restrict__ Bsw, const unsigned short* __restrict__ Asw,
    const float* __restrict__ g, const float* __restrict__ be,
    const float* __restrict__ mu, const float* __restrict__ var,
    const unsigned short* __restrict__ xb, float* __restrict__ out) {
    __shared__ __align__(16) unsigned short lAb[4][8 * 512];
    __shared__ __align__(16) unsigned short lBb[4][7 * 512];
    int b = blockIdx.x, y = blockIdx.y, mh = y >> 1, nh = y & 1;
    int tid = threadIdx.x, wv = tid >> 6, grp = wv >> 2, wl = wv & 3;
    int lane = tid & 63, lo = lane & 15, g4 = lane >> 4;
    const unsigned short* Ab = Asw + (size_t)(b * 64 + mh * 8) * 8 * 512;
    const unsigned short* Bb = Bsw + (size_t)(b * 14 + nh * 7) * 8 * 512;
    f32x4 acc0[7], acc1[7];
#pragma unroll
    for (int t = 0; t < 7; t++) { acc0[t] = {0.f, 0.f, 0.f, 0.f}; acc1[t] = {0.f, 0.f, 0.f, 0.f}; }

    auto stage = [&](int kt, unsigned short* lA, unsigned short* lB) {
        gl2lds(Ab + ((size_t)wl * 8 + kt) * 512 + lane * 8, lA + wl * 512, lane);
        gl2lds(Ab + ((size_t)(wl + 4) * 8 + kt) * 512 + lane * 8, lA + (wl + 4) * 512, lane);
        gl2lds(Bb + ((size_t)wl * 8 + kt) * 512 + lane * 8, lB + wl * 512, lane);
        if (wl < 3)
            gl2lds(Bb + ((size_t)(4 + wl) * 8 + kt) * 512 + lane * 8, lB + (4 + wl) * 512, lane);
    };
    auto compute = [&](const unsigned short* lA, const unsigned short* lB) {
        bf16x8 a0 = *(const bf16x8*)(lA + wl * 512 + lane * 8);
        bf16x8 a1 = *(const bf16x8*)(lA + (wl + 4) * 512 + lane * 8);
#pragma unroll
        for (int t = 0; t < 7; t++) {
            bf16x8 bt = *(const bf16x8*)(lB + t * 512 + lane * 8);
            acc0[t] = __builtin_amdgcn_mfma_f32_16x16x32_bf16(a0, bt, acc0[t], 0, 0, 0);
            acc1[t] = __builtin_amdgcn_mfma_f32_16x16x32_bf16(a1, bt, acc1[t], 0, 0, 0);
        }
    };

    stage(grp, lAb[grp], lBb[grp]);
    for (int kp = 0; kp < 4; kp++) {
        __syncthreads();
        if (kp < 3) {
            int s = 2 * kp + 2 + grp;
            stage(s, lAb[s & 3], lBb[s & 3]);
        }
        int c = (2 * kp + grp) & 3;
        compute(lAb[c], lBb[c]);
    }
    __syncthreads();
    float* red = (float*)&lBb[0][0];
    if (grp == 1) {
#pragma unroll
        for (int t = 0; t < 7; t++)
            *(f32x4*)(red + (((size_t)wl * 7 + t) * 64 + lane) * 4) = acc0[t];
    }
    __syncthreads();
    if (grp == 0) {
#pragma unroll
        for (int t = 0; t < 7; t++) {
            f32x4 o = *(const f32x4*)(red + (((size_t)wl * 7 + t) * 64 + lane) * 4);
#pragma unroll
            for (int r = 0; r < 4; r++) acc0[t][r] += o[r];
        }
    }
    __syncthreads();
    if (grp == 1) {
#pragma unroll
        for (int t = 0; t < 7; t++)
            *(f32x4*)(red + (((size_t)wl * 7 + t) * 64 + lane) * 4) = acc1[t];
    }
    __syncthreads();
    if (grp != 0) return;
#pragma unroll
    for (int t = 0; t < 7; t++) {
        f32x4 o = *(const f32x4*)(red + (((size_t)wl * 7 + t) * 64 + lane) * 4);
#pragma unroll
        for (int r = 0; r < 4; r++) acc1[t][r] += o[r];
    }

#pragma unroll
    for (int a = 0; a < 2; a++) {
        int mt = mh * 8 + wl + 4 * a;
        int c0 = mt * 16 + g4 * 4;
        float sc[4], sh[4];
#pragma unroll
        for (int r = 0; r < 4; r++) {
            float iv = rsqrtf(var[c0 + r] + EPS) * g[c0 + r];
            sc[r] = iv;
            sh[r] = be[c0 + r] - mu[c0 + r] * iv;
        }
        int ktc = mt >> 1;
        int lanehi = ((mt * 2 + (g4 >> 1)) & 3) << 4;
#pragma unroll
        for (int t = 0; t < 7; t++) {
            int nt = nh * 7 + t;
            int n = nt * 16 + lo;
            if (n >= HW) continue;
            const unsigned short* xr = xb + (((size_t)(b * 14 + nt)) * 32 + ktc) * 512
                                       + (size_t)(lo | lanehi) * 8 + (g4 & 1) * 4;
            uint2 rv = *(const uint2*)xr;
            float res[4] = {bf2f((unsigned short)(rv.x & 0xffff)),
                            bf2f((unsigned short)(rv.x >> 16)),
                            bf2f((unsigned short)(rv.y & 0xffff)),
                            bf2f((unsigned short)(rv.y >> 16))};
            f32x4 av = a ? acc1[t] : acc0[t];
#pragma unroll
            for (int r = 0; r < 4; r++) {
                size_t oidx = ((size_t)(b * OUTP + c0 + r)) * HW + n;
                float val = av[r] * sc[r] + sh[r] + res[r];
                out[oidx] = fmaxf(val, 0.f);
            }
        }
    }
}

// ---------------------------------------------------------------------------
extern "C" void kernel_launch(void* const* d_in, const int* in_sizes, int n_in,
                              void* d_out, int out_size, void* d_ws, size_t ws_size,
                              hipStream_t stream) {
    const float* x    = (const float*)d_in[0];
    const float* w1   = (const float*)d_in[1];
    const float* w2   = (const float*)d_in[2];
    const float* w3   = (const float*)d_in[3];
    const float* r1_w = (const float*)d_in[4];
    const float* r1_b = (const float*)d_in[5];
    const float* r2_w = (const float*)d_in[6];
    const float* r2_b = (const float*)d_in[7];
    const float* r3_w = (const float*)d_in[8];
    const float* r3_b = (const float*)d_in[9];
    const float* bn1_g = (const float*)d_in[10];
    const float* bn1_b = (const float*)d_in[11];
    const float* bn1_m = (const float*)d_in[12];
    const float* bn1_v = (const float*)d_in[13];
    const float* bn2_g = (const float*)d_in[14];
    const float* bn2_b = (const float*)d_in[15];
    const float* bn2_m = (const float*)d_in[16];
    const float* bn2_v = (const float*)d_in[17];
    const float* bn3_g = (const float*)d_in[18];
    const float* bn3_b = (const float*)d_in[19];
    const float* bn3_m = (const float*)d_in[20];
    const float* bn3_v = (const float*)d_in[21];
    float* out = (float*)d_out;

    // Workspace (~86.4 MB). cwX slot time-shared: cw1 (stage 1) then cw3
    // (stage 3; cw1 dead after gemm1). xb persists to gemm3 (bf16 residual).
    char* ws = (char*)d_ws;
    size_t off = 0;
    float* mean1 = (float*)(ws + off); off += (size_t)BB * INP * 4;
    float* msum2 = (float*)(ws + off); off += (size_t)BB * 256 * 4;
    float* msum3 = (float*)(ws + off); off += (size_t)BB * 256 * 4;
    unsigned short* zpad = (unsigned short*)(ws + off); off += 256;
    off = (off + 255) & ~(size_t)255;
    unsigned short* act1 = (unsigned short*)(ws + off); off += (size_t)BB * 14 * 8 * 512 * 2;  // 3.67 MB
    unsigned short* act2 = (unsigned short*)(ws + off); off += (size_t)BB * 14 * 8 * 512 * 2;  // 3.67 MB
    unsigned short* cw2 = (unsigned short*)(ws + off); off += (size_t)BB * 16 * 72 * 512 * 2;  // 37.75 MB
    unsigned short* xb  = (unsigned short*)(ws + off); off += (size_t)BB * 14 * 32 * 512 * 2;  // 14.68 MB
    unsigned short* wb2 = (unsigned short*)(ws + off); off += (size_t)S2 * NE * 2;             // 9.44 MB
    unsigned short* cwX = (unsigned short*)(ws + off); off += (size_t)BB * S1 * 2;             // 16.78 MB
    unsigned short* cw1 = cwX;
    unsigned short* cw3 = cwX;
    (void)ws_size;

    // Pre: transpose+mean of x (blocks 0-255) || permute w2 + zero
    // msum2/msum3/zpad (blocks 256-2303). Memset dispatch eliminated.
    pre_kernel<<<2304, 256, 0, stream>>>(x, xb, mean1, w2, wb2, zpad, msum2, msum3);

    // Stage 1: 1x1 conv 1024->256
    combine_cont_r<<<dim3(128, 4), 256, 0, stream>>>(w1, mean1, r1_w, r1_b, 1.0f, INP,
                                                     cw1, S1, 16, 32);
    gemm1_fused<<<dim3(BB, 4, 4), 512, 0, stream>>>(xb, cw1, bn1_g, bn1_b, bn1_m, bn1_v,
                                                    act1, msum2);

    // Stage 2: 3x3 conv 256->256
    combine_w2_r<<<dim3(288, 4), 256, 0, stream>>>(wb2, msum2, r2_w, r2_b,
                                                   1.0f / (float)HW, cw2);
    gemm2_fused<<<dim3(BB, 8, 2), 512, 0, stream>>>(act1, cw2, zpad, bn2_g, bn2_b,
                                                    bn2_m, bn2_v, act2, msum3);

    // Stage 3: 1x1 conv 256->1024 + residual
    combine_cont_r<<<dim3(128, 4), 256, 0, stream>>>(w3, msum3, r3_w, r3_b,
                                                     1.0f / (float)HW, WIDTH,
                                                     cw3, S3, 64, 8);
    gemm3_fused<<<dim3(BB, 16), 512, 0, stream>>>(act2, cw3, bn3_g, bn3_b, bn3_m, bn3_v,
                                                  xb, out);
}

// Round 5
// 240.830 us; speedup vs baseline: 1.2063x; 1.0126x over previous
//
#include <hip/hip_runtime.h>
#include <hip/hip_bf16.h>

#define BB 32
#define INP 1024
#define WIDTH 256
#define OUTP 1024
#define NE 8
#define HW 196
#define HH 14
#define EPS 1e-5f

#define S1 (WIDTH * INP)        // 262144
#define S2 (WIDTH * WIDTH * 9)  // 589824
#define S3 (OUTP * WIDTH)       // 262144

typedef __attribute__((ext_vector_type(8))) short bf16x8;
typedef __attribute__((ext_vector_type(4))) float f32x4;
typedef __attribute__((ext_vector_type(8))) unsigned short u16x8;

// Swizzled operand layout: tile = 16 rows x 32 k = 512 bf16 = 1 KB.
// Element (r,k) at lane*8 + (k&7), lane = (r&15) | (((k>>3)&3)<<4).

// Counted-vmcnt drain (T4): keep the newest in-flight batch across the
// barrier; only the tail drains to 0.
#define VMCNT(n) asm volatile("s_waitcnt vmcnt(" #n ")" ::: "memory")

__device__ __forceinline__ unsigned short f2bf_bits(float f) {
    unsigned u = __float_as_uint(f);
    u += 0x7FFFu + ((u >> 16) & 1u);   // RNE
    return (unsigned short)(u >> 16);
}
__device__ __forceinline__ float bf2f(unsigned short h) {
    return __uint_as_float((unsigned)h << 16);
}

#if defined(__has_builtin)
#if __has_builtin(__builtin_amdgcn_global_load_lds)
#define HAVE_GLL 1
#endif
#endif
__device__ __forceinline__ void gl2lds(const unsigned short* g, unsigned short* l,
                                       int lane) {
#ifdef HAVE_GLL
    __builtin_amdgcn_global_load_lds(
        (const __attribute__((address_space(1))) unsigned int*)(const void*)g,
        (__attribute__((address_space(3))) unsigned int*)(void*)l, 16, 0, 0);
#else
    *(u16x8*)(l + lane * 8) = *(const u16x8*)g;
#endif
}

// ---------------------------------------------------------------------------
// In-block routing (8-sample group g): srw[s*8+e] = sigmoid(scale*(v@W)+b).
// Called once per block (g = blockIdx.y). Occupancy > L3-traffic savings:
// do NOT fold sample-groups into a block loop (round-3 regression, 4.6% occ).
// ---------------------------------------------------------------------------
__device__ __forceinline__ void block_route(
    const float* __restrict__ vec, const float* __restrict__ W,
    const float* __restrict__ bias, float scale, int C, int g,
    float* srw, int tid) {
    int wv = tid >> 6, lane = tid & 63;
    float p0[NE], p1[NE];
#pragma unroll
    for (int e = 0; e < NE; e++) { p0[e] = 0.f; p1[e] = 0.f; }
    const float* v0 = vec + (size_t)(g * 8 + wv * 2) * C;
    const float* v1 = v0 + C;
    for (int c = lane; c < C; c += 64) {
        float4 wa = *(const float4*)(W + c * 8);
        float4 wb = *(const float4*)(W + c * 8 + 4);
        float m0 = v0[c], m1 = v1[c];
        p0[0] += m0 * wa.x; p0[1] += m0 * wa.y; p0[2] += m0 * wa.z; p0[3] += m0 * wa.w;
        p0[4] += m0 * wb.x; p0[5] += m0 * wb.y; p0[6] += m0 * wb.z; p0[7] += m0 * wb.w;
        p1[0] += m1 * wa.x; p1[1] += m1 * wa.y; p1[2] += m1 * wa.z; p1[3] += m1 * wa.w;
        p1[4] += m1 * wb.x; p1[5] += m1 * wb.y; p1[6] += m1 * wb.z; p1[7] += m1 * wb.w;
    }
#pragma unroll
    for (int j = 1; j < 64; j <<= 1) {
#pragma unroll
        for (int e = 0; e < NE; e++) {
            p0[e] += __shfl_xor(p0[e], j, 64);
            p1[e] += __shfl_xor(p1[e], j, 64);
        }
    }
    if (lane == 0) {
#pragma unroll
        for (int e = 0; e < NE; e++) {
            srw[(wv * 2) * 8 + e] = 1.0f / (1.0f + expf(-(scale * p0[e] + bias[e])));
            srw[(wv * 2 + 1) * 8 + e] = 1.0f / (1.0f + expf(-(scale * p1[e] + bias[e])));
        }
    }
    __syncthreads();
}

// ---------------------------------------------------------------------------
// Merged pre-kernel. Blocks [0,256): transpose+mean of x -> swizzled xb +
// mean1. Blocks [256,2304): permute w2 -> k-ordered bf16 wb2; blocks
// 256..287 also zero msum2/msum3; block 256 zeroes zpad (replaces memset).
// ---------------------------------------------------------------------------
__global__ __launch_bounds__(256) void pre_kernel(
    const float* __restrict__ x, unsigned short* __restrict__ xb,
    float* __restrict__ mean1,
    const float* __restrict__ w2, unsigned short* __restrict__ wb2,
    unsigned short* __restrict__ zpad,
    float* __restrict__ msum2, float* __restrict__ msum3) {
    __shared__ __align__(16) char smem[128 * 17 * 4];
    int blk = blockIdx.x, t = threadIdx.x;
    if (blk < 256) {
        float (*lt)[17] = (float(*)[17])smem;
        int b = blk >> 3, yq = blk & 7, c0 = yq * 128;
        int cr = t >> 1, half = t & 1;
        const float* src = x + ((size_t)(b * INP + c0 + cr)) * HW;
        float msum = 0.f;
        int j = t >> 4, nl = t & 15;
        for (int pg = 0; pg < 14; pg++) {
            int p0 = pg * 16 + half * 8;
            float vv[8];
            if (pg < 12) {
                float4 a = *(const float4*)(src + p0);
                float4 c = *(const float4*)(src + p0 + 4);
                vv[0] = a.x; vv[1] = a.y; vv[2] = a.z; vv[3] = a.w;
                vv[4] = c.x; vv[5] = c.y; vv[6] = c.z; vv[7] = c.w;
            } else {
#pragma unroll
                for (int i = 0; i < 8; i++) {
                    int p = p0 + i;
                    vv[i] = (p < HW) ? src[p] : 0.f;
                }
            }
#pragma unroll
            for (int i = 0; i < 8; i++) { msum += vv[i]; lt[cr][half * 8 + i] = vv[i]; }
            __syncthreads();
            unsigned short pk[8];
#pragma unroll
            for (int i = 0; i < 8; i++) pk[i] = f2bf_bits(lt[j * 8 + i][nl]);
            size_t tile = ((size_t)b * 14 + pg) * 32 + (size_t)(yq * 4 + (j >> 2));
            int lane = nl | ((j & 3) << 4);
            *(u16x8*)(xb + tile * 512 + lane * 8) = *(u16x8*)pk;
            __syncthreads();
        }
        float other = __shfl_xor(msum, 1, 64);
        if (half == 0) mean1[b * INP + c0 + cr] = (msum + other) * (1.0f / (float)HW);
    } else {
        unsigned short* lds = (unsigned short*)smem;
        int eo = blk - 256;
        // Fold the old hipMemsetAsync: zero msum2/msum3 (32*256 floats each)
        // and the first 16 B of zpad.
        if (eo < 32) {
            int idx = eo * 256 + t;
            msum2[idx] = 0.f;
            msum3[idx] = 0.f;
            if (eo == 0 && t == 0) {
                u16x8 z = {0, 0, 0, 0, 0, 0, 0, 0};
                *(u16x8*)zpad = z;
            }
        }
        const float* src = w2 + (size_t)eo * 2304 + (size_t)t * 9;
#pragma unroll
        for (int t9 = 0; t9 < 9; t9++) lds[t9 * 256 + t] = f2bf_bits(src[t9]);
        __syncthreads();
        unsigned short* dst = wb2 + (size_t)eo * 2304;
        for (int j = t; j < 288; j += 256)
            *(u16x8*)(dst + j * 8) = *(const u16x8*)(lds + j * 8);
    }
}

// ---------------------------------------------------------------------------
// Combine (contiguous-k fp32 experts, w1/w3) + fused routing.
// grid = (Mt*Kt/4, 4 sample groups), 256 threads. Weight re-reads across
// the 4 y-blocks are L3-absorbed (measured FETCH ~5 MB) — keep the grid fat.
// ---------------------------------------------------------------------------
__global__ __launch_bounds__(256) void combine_cont_r(
    const float* __restrict__ w, const float* __restrict__ vec,
    const float* __restrict__ rW, const float* __restrict__ rB, float scale, int C,
    unsigned short* __restrict__ cw, int S, int Mt, int Kt) {
    __shared__ float srw[64];
    int tid = threadIdx.x, wv = tid >> 6, lane = tid & 63, ml = lane & 15, k8l = lane >> 4;
    int g = blockIdx.y;
    block_route(vec, rW, rB, scale, C, g, srw, tid);
    int kq = Kt >> 2;
    int mt = blockIdx.x / kq, kt = (blockIdx.x - mt * kq) * 4 + wv;
    int K = Kt * 32;
    const float* src = w + (size_t)(mt * 16 + ml) * K + kt * 32 + k8l * 8;
    float v[NE][8];
#pragma unroll
    for (int e = 0; e < NE; e++) {
        float4 a = *(const float4*)(src + (size_t)e * S);
        float4 c = *(const float4*)(src + (size_t)e * S + 4);
        v[e][0] = a.x; v[e][1] = a.y; v[e][2] = a.z; v[e][3] = a.w;
        v[e][4] = c.x; v[e][5] = c.y; v[e][6] = c.z; v[e][7] = c.w;
    }
    size_t dto = ((size_t)mt * Kt + kt) * 512 + (size_t)lane * 8;
    size_t bstr = (size_t)Mt * Kt * 512;
    for (int bl = 0; bl < 8; bl++) {
        int b = g * 8 + bl;
        float acc[8];
#pragma unroll
        for (int jj = 0; jj < 8; jj++) acc[jj] = 0.f;
#pragma unroll
        for (int e = 0; e < NE; e++) {
            float r = srw[bl * NE + e];
#pragma unroll
            for (int jj = 0; jj < 8; jj++) acc[jj] += r * v[e][jj];
        }
        u16x8 o;
#pragma unroll
        for (int jj = 0; jj < 8; jj++) o[jj] = f2bf_bits(acc[jj]);
        *(u16x8*)(cw + (size_t)b * bstr + dto) = o;
    }
}

// ---------------------------------------------------------------------------
// Combine w2 (k-ordered bf16 wb2) + fused routing. grid = (288, 4 groups).
// ---------------------------------------------------------------------------
__global__ __launch_bounds__(256) void combine_w2_r(
    const unsigned short* __restrict__ wb2, const float* __restrict__ vec,
    const float* __restrict__ rW, const float* __restrict__ rB, float scale,
    unsigned short* __restrict__ cw) {
    __shared__ float srw[64];
    int tid = threadIdx.x, wv = tid >> 6, lane = tid & 63, ol = lane & 15, g4 = lane >> 4;
    int g = blockIdx.y;
    block_route(vec, rW, rB, scale, 256, g, srw, tid);
    int ot = blockIdx.x / 18, kt = (blockIdx.x - ot * 18) * 4 + wv;
    const unsigned short* src = wb2 + (size_t)(ot * 16 + ol) * 2304 + kt * 32 + g4 * 8;
    float v[NE][8];
#pragma unroll
    for (int e = 0; e < NE; e++) {
        u16x8 raw = *(const u16x8*)(src + (size_t)e * S2);
#pragma unroll
        for (int jj = 0; jj < 8; jj++) v[e][jj] = bf2f(raw[jj]);
    }
    size_t dto = ((size_t)ot * 72 + kt) * 512 + (size_t)lane * 8;
    for (int bl = 0; bl < 8; bl++) {
        int b = g * 8 + bl;
        float acc[8];
#pragma unroll
        for (int jj = 0; jj < 8; jj++) acc[jj] = 0.f;
#pragma unroll
        for (int e = 0; e < NE; e++) {
            float r = srw[bl * NE + e];
#pragma unroll
            for (int jj = 0; jj < 8; jj++) acc[jj] += r * v[e][jj];
        }
        u16x8 out;
#pragma unroll
        for (int jj = 0; jj < 8; jj++) out[jj] = f2bf_bits(acc[jj]);
        *(u16x8*)(cw + (size_t)b * (16 * 72 * 512) + dto) = out;
    }
}

// ---------------------------------------------------------------------------
// Fused epilogue: BN + ReLU -> swizzled bf16 act + per-channel sum atomics.
// Handles nB (3 or 4) n-tiles starting at nt0.
// ---------------------------------------------------------------------------
__device__ __forceinline__ void epilogue_act(
    const f32x4* acc, int b, int mt, int nt0, int nB, int lo, int g4,
    const float* __restrict__ g, const float* __restrict__ be,
    const float* __restrict__ mu, const float* __restrict__ var,
    unsigned short* __restrict__ actout, float* __restrict__ msum) {
    int c0 = mt * 16 + g4 * 4;
    float sc[4], sh[4];
#pragma unroll
    for (int r = 0; r < 4; r++) {
        float iv = rsqrtf(var[c0 + r] + EPS) * g[c0 + r];
        sc[r] = iv;
        sh[r] = be[c0 + r] - mu[c0 + r] * iv;
    }
    float ms[4] = {0.f, 0.f, 0.f, 0.f};
    int ktc = mt >> 1;
    int lanehi = ((mt * 2 + (g4 >> 1)) & 3) << 4;
#pragma unroll
    for (int t = 0; t < 4; t++) {
        if (t >= nB) break;
        int nt = nt0 + t;
        int n = nt * 16 + lo;
        float v[4];
#pragma unroll
        for (int r = 0; r < 4; r++) {
            float val = acc[t][r] * sc[r] + sh[r];
            val = fmaxf(val, 0.f);
            if (n >= HW) val = 0.f;
            v[r] = val;
            ms[r] += val;
        }
        unsigned p01 = (unsigned)f2bf_bits(v[0]) | ((unsigned)f2bf_bits(v[1]) << 16);
        unsigned p23 = (unsigned)f2bf_bits(v[2]) | ((unsigned)f2bf_bits(v[3]) << 16);
        size_t off = (((size_t)(b * 14 + nt)) * 8 + ktc) * 512 + (size_t)(lo | lanehi) * 8 + (g4 & 1) * 4;
        *(uint2*)(actout + off) = make_uint2(p01, p23);
    }
#pragma unroll
    for (int r = 0; r < 4; r++) {
        float s = ms[r];
        s += __shfl_xor(s, 1, 64);
        s += __shfl_xor(s, 2, 64);
        s += __shfl_xor(s, 4, 64);
        s += __shfl_xor(s, 8, 64);
        if (lo == 0) atomicAdd(&msum[b * 256 + c0 + r], s);
    }
}

// ---------------------------------------------------------------------------
// Stage-1 fused GEMM, 512 threads = 8 waves, in-block split-K2.
// n-axis split in 4 chunks (4,4,3,3 tiles) -> grid (BB,4,4) = 512 blocks
// = 2 blocks/CU. 8 LDS buffers (64 KB), distance-2 staging, counted vmcnt:
// the two positive axes (occupancy + pipeline depth) combined.
// Buffer parity: group 0 computes even k-steps (bufs 0,2,4,6), group 1 odd.
// ---------------------------------------------------------------------------
__global__ __launch_bounds__(512) void gemm1_fused(
    const unsigned short* __restrict__ Bsw, const unsigned short* __restrict__ Asw,
    const float* __restrict__ g, const float* __restrict__ be,
    const float* __restrict__ mu, const float* __restrict__ var,
    unsigned short* __restrict__ actout, float* __restrict__ msum) {
    __shared__ __align__(16) unsigned short lAb[8][4 * 512];   // 32 KB
    __shared__ __align__(16) unsigned short lBb[8][4 * 512];   // 32 KB
    const int Kt = 32;
    int b = blockIdx.x, mh = blockIdx.y, z = blockIdx.z;
    int nt0 = (z < 3) ? z * 4 : 11;
    int nB = (z < 2) ? 4 : 3;
    int tid = threadIdx.x, wv = tid >> 6, grp = wv >> 2, wl = wv & 3;
    int lane = tid & 63, lo = lane & 15, g4 = lane >> 4;
    const unsigned short* Ab = Asw + (size_t)(b * 16 + mh * 4) * Kt * 512;
    const unsigned short* Bb = Bsw + (size_t)(b * 14 + nt0) * Kt * 512;
    f32x4 acc[4];
#pragma unroll
    for (int t = 0; t < 4; t++) acc[t] = {0.f, 0.f, 0.f, 0.f};

    auto stage = [&](int kt) {
        unsigned short* lA = lAb[kt & 7];
        unsigned short* lB = lBb[kt & 7];
        gl2lds(Ab + ((size_t)wl * Kt + kt) * 512 + lane * 8, lA + wl * 512, lane);
        if (wl < nB)
            gl2lds(Bb + ((size_t)wl * Kt + kt) * 512 + lane * 8, lB + wl * 512, lane);
    };
    auto compute = [&](int kt) {
        const unsigned short* lA = lAb[kt & 7];
        const unsigned short* lB = lBb[kt & 7];
        bf16x8 a0 = *(const bf16x8*)(lA + wl * 512 + lane * 8);
#pragma unroll
        for (int t = 0; t < 4; t++) {
            if (t >= nB) break;
            bf16x8 bt = *(const bf16x8*)(lB + t * 512 + lane * 8);
            acc[t] = __builtin_amdgcn_mfma_f32_16x16x32_bf16(a0, bt, acc[t], 0, 0, 0);
        }
    };

    // Two batches of this group's parity in flight.
    stage(grp);
    stage(grp + 2);
    for (int kp = 0; kp < 16; kp++) {
        int c = 2 * kp + grp;
        if (c + 2 < 32) {
            // Drain so batch c is complete; batch c+2 stays in flight.
            if (wl < nB) VMCNT(2); else VMCNT(1);
        } else {
            VMCNT(0);
        }
        __builtin_amdgcn_s_barrier();
        int s = c + 4;
        if (s < 32) stage(s);
        compute(c);
    }
    __syncthreads();
    float* red = (float*)&lBb[0][0];   // 16 KB
    if (grp == 1) {
#pragma unroll
        for (int t = 0; t < 4; t++)
            *(f32x4*)(red + (((size_t)wl * 4 + t) * 64 + lane) * 4) = acc[t];
    }
    __syncthreads();
    if (grp == 0) {
#pragma unroll
        for (int t = 0; t < 4; t++) {
            f32x4 o = *(const f32x4*)(red + (((size_t)wl * 4 + t) * 64 + lane) * 4);
#pragma unroll
            for (int r = 0; r < 4; r++) acc[t][r] += o[r];
        }
        epilogue_act(acc, b, mh * 4 + wl, nt0, nB, lo, g4, g, be, mu, var, actout, msum);
    }
}

// ---------------------------------------------------------------------------
// Stage-2 fused GEMM (im2col gather staging), 512 threads, in-block split-K2.
// Grid (BB,4,4) — the measured-good blocking (round-2) — with 8 LDS buffers
// (64 KB), distance-2 staging and counted vmcnt. 72 k-steps (9 taps x 8
// i-tiles). 2 blocks/CU.
// ---------------------------------------------------------------------------
__global__ __launch_bounds__(512) void gemm2_fused(
    const unsigned short* __restrict__ act, const unsigned short* __restrict__ cw2,
    const unsigned short* __restrict__ zpad,
    const float* __restrict__ g, const float* __restrict__ be,
    const float* __restrict__ mu, const float* __restrict__ var,
    unsigned short* __restrict__ actout, float* __restrict__ msum) {
    __shared__ __align__(16) unsigned short lAb[8][4 * 512];   // 32 KB
    __shared__ __align__(16) unsigned short lBb[8][4 * 512];   // 32 KB
    int b = blockIdx.x, mh = blockIdx.y, z = blockIdx.z;
    int nt0 = (z < 3) ? z * 4 : 11;
    int nB = (z < 2) ? 4 : 3;
    int tid = threadIdx.x, wv = tid >> 6, grp = wv >> 2, wl = wv & 3;
    int lane = tid & 63, lo = lane & 15, g4 = lane >> 4;
    const unsigned short* Ab = cw2 + (size_t)(b * 16 + mh * 4) * 72 * 512;
    const unsigned short* actb = act + (size_t)b * 14 * 8 * 512;

    int p0 = (nt0 + wl) * 16 + lo;
    int py0 = p0 / HH, px0 = p0 - (p0 / HH) * HH;
    bool pv0 = (wl < nB) && (p0 < HW);

    f32x4 acc[4];
#pragma unroll
    for (int t = 0; t < 4; t++) acc[t] = {0.f, 0.f, 0.f, 0.f};

    auto stage = [&](int kt) {
        unsigned short* lA = lAb[kt & 7];
        unsigned short* lB = lBb[kt & 7];
        gl2lds(Ab + ((size_t)wl * 72 + kt) * 512 + lane * 8, lA + wl * 512, lane);
        if (wl < nB) {
            int t9 = kt >> 3;
            int dy = t9 / 3 - 1, dx = t9 - (t9 / 3) * 3 - 1;
            int itile = kt & 7;
            int sy = py0 + dy, sx = px0 + dx;
            bool ok = pv0 && sy >= 0 && sy < HH && sx >= 0 && sx < HH;
            int ns = sy * HH + sx;
            const unsigned short* gp = ok
                ? actb + ((size_t)(ns >> 4) * 8 + itile) * 512 + (size_t)((ns & 15) | (g4 << 4)) * 8
                : zpad;
            gl2lds(gp, lB + wl * 512, lane);
        }
    };
    auto compute = [&](int kt) {
        const unsigned short* lA = lAb[kt & 7];
        const unsigned short* lB = lBb[kt & 7];
        bf16x8 a0 = *(const bf16x8*)(lA + wl * 512 + lane * 8);
#pragma unroll
        for (int t = 0; t < 4; t++) {
            if (t >= nB) break;
            bf16x8 bt = *(const bf16x8*)(lB + t * 512 + lane * 8);
            acc[t] = __builtin_amdgcn_mfma_f32_16x16x32_bf16(a0, bt, acc[t], 0, 0, 0);
        }
    };

    stage(grp);
    stage(grp + 2);
    for (int kp = 0; kp < 36; kp++) {
        int c = 2 * kp + grp;
        if (c + 2 < 72) {
            if (wl < nB) VMCNT(2); else VMCNT(1);
        } else {
            VMCNT(0);
        }
        __builtin_amdgcn_s_barrier();
        int s = c + 4;
        if (s < 72) stage(s);
        compute(c);
    }
    __syncthreads();
    float* red = (float*)&lBb[0][0];   // 16 KB
    if (grp == 1) {
#pragma unroll
        for (int t = 0; t < 4; t++)
            *(f32x4*)(red + (((size_t)wl * 4 + t) * 64 + lane) * 4) = acc[t];
    }
    __syncthreads();
    if (grp == 0) {
#pragma unroll
        for (int t = 0; t < 4; t++) {
            f32x4 o = *(const f32x4*)(red + (((size_t)wl * 4 + t) * 64 + lane) * 4);
#pragma unroll
            for (int r = 0; r < 4; r++) acc[t][r] += o[r];
        }
        epilogue_act(acc, b, mh * 4 + wl, nt0, nB, lo, g4, g, be, mu, var, actout, msum);
    }
}

// ---------------------------------------------------------------------------
// Stage-3 GEMM, 512 threads, in-block split-K2, fused BN + bf16 residual
// (from swizzled xb) + ReLU -> fp32 NCHW. grid (BB, 16) = 512 blocks
// (2 blocks/CU at 60 KB LDS). K=256 (8 steps). Unchanged (measured-good).
// ---------------------------------------------------------------------------
__global__ __launch_bounds__(512) void gemm3_fused(
    const unsigned short* __restrict__ Bsw, const unsigned short* __restrict__ Asw,
    const float* __restrict__ g, const float* __restrict__ be,
    const float* __restrict__ mu, const float* __restrict__ var,
    const unsigned short* __restrict__ xb, float* __restrict__ out) {
    __shared__ __align__(16) unsigned short lAb[4][8 * 512];
    __shared__ __align__(16) unsigned short lBb[4][7 * 512];
    int b = blockIdx.x, y = blockIdx.y, mh = y >> 1, nh = y & 1;
    int tid = threadIdx.x, wv = tid >> 6, grp = wv >> 2, wl = wv & 3;
    int lane = tid & 63, lo = lane & 15, g4 = lane >> 4;
    const unsigned short* Ab = Asw + (size_t)(b * 64 + mh * 8) * 8 * 512;
    const unsigned short* Bb = Bsw + (size_t)(b * 14 + nh * 7) * 8 * 512;
    f32x4 acc0[7], acc1[7];
#pragma unroll
    for (int t = 0; t < 7; t++) { acc0[t] = {0.f, 0.f, 0.f, 0.f}; acc1[t] = {0.f, 0.f, 0.f, 0.f}; }

    auto stage = [&](int kt, unsigned short* lA, unsigned short* lB) {
        gl2lds(Ab + ((size_t)wl * 8 + kt) * 512 + lane * 8, lA + wl * 512, lane);
        gl2lds(Ab + ((size_t)(wl + 4) * 8 + kt) * 512 + lane * 8, lA + (wl + 4) * 512, lane);
        gl2lds(Bb + ((size_t)wl * 8 + kt) * 512 + lane * 8, lB + wl * 512, lane);
        if (wl < 3)
            gl2lds(Bb + ((size_t)(4 + wl) * 8 + kt) * 512 + lane * 8, lB + (4 + wl) * 512, lane);
    };
    auto compute = [&](const unsigned short* lA, const unsigned short* lB) {
        bf16x8 a0 = *(const bf16x8*)(lA + wl * 512 + lane * 8);
        bf16x8 a1 = *(const bf16x8*)(lA + (wl + 4) * 512 + lane * 8);
#pragma unroll
        for (int t = 0; t < 7; t++) {
            bf16x8 bt = *(const bf16x8*)(lB + t * 512 + lane * 8);
            acc0[t] = __builtin_amdgcn_mfma_f32_16x16x32_bf16(a0, bt, acc0[t], 0, 0, 0);
            acc1[t] = __builtin_amdgcn_mfma_f32_16x16x32_bf16(a1, bt, acc1[t], 0, 0, 0);
        }
    };

    stage(grp, lAb[grp], lBb[grp]);
    for (int kp = 0; kp < 4; kp++) {
        __syncthreads();
        if (kp < 3) {
            int s = 2 * kp + 2 + grp;
            stage(s, lAb[s & 3], lBb[s & 3]);
        }
        int c = (2 * kp + grp) & 3;
        compute(lAb[c], lBb[c]);
    }
    __syncthreads();
    float* red = (float*)&lBb[0][0];
    if (grp == 1) {
#pragma unroll
        for (int t = 0; t < 7; t++)
            *(f32x4*)(red + (((size_t)wl * 7 + t) * 64 + lane) * 4) = acc0[t];
    }
    __syncthreads();
    if (grp == 0) {
#pragma unroll
        for (int t = 0; t < 7; t++) {
            f32x4 o = *(const f32x4*)(red + (((size_t)wl * 7 + t) * 64 + lane) * 4);
#pragma unroll
            for (int r = 0; r < 4; r++) acc0[t][r] += o[r];
        }
    }
    __syncthreads();
    if (grp == 1) {
#pragma unroll
        for (int t = 0; t < 7; t++)
            *(f32x4*)(red + (((size_t)wl * 7 + t) * 64 + lane) * 4) = acc1[t];
    }
    __syncthreads();
    if (grp != 0) return;
#pragma unroll
    for (int t = 0; t < 7; t++) {
        f32x4 o = *(const f32x4*)(red + (((size_t)wl * 7 + t) * 64 + lane) * 4);
#pragma unroll
        for (int r = 0; r < 4; r++) acc1[t][r] += o[r];
    }

#pragma unroll
    for (int a = 0; a < 2; a++) {
        int mt = mh * 8 + wl + 4 * a;
        int c0 = mt * 16 + g4 * 4;
        float sc[4], sh[4];
#pragma unroll
        for (int r = 0; r < 4; r++) {
            float iv = rsqrtf(var[c0 + r] + EPS) * g[c0 + r];
            sc[r] = iv;
            sh[r] = be[c0 + r] - mu[c0 + r] * iv;
        }
        int ktc = mt >> 1;
        int lanehi = ((mt * 2 + (g4 >> 1)) & 3) << 4;
#pragma unroll
        for (int t = 0; t < 7; t++) {
            int nt = nh * 7 + t;
            int n = nt * 16 + lo;
            if (n >= HW) continue;
            const unsigned short* xr = xb + (((size_t)(b * 14 + nt)) * 32 + ktc) * 512
                                       + (size_t)(lo | lanehi) * 8 + (g4 & 1) * 4;
            uint2 rv = *(const uint2*)xr;
            float res[4] = {bf2f((unsigned short)(rv.x & 0xffff)),
                            bf2f((unsigned short)(rv.x >> 16)),
                            bf2f((unsigned short)(rv.y & 0xffff)),
                            bf2f((unsigned short)(rv.y >> 16))};
            f32x4 av = a ? acc1[t] : acc0[t];
#pragma unroll
            for (int r = 0; r < 4; r++) {
                size_t oidx = ((size_t)(b * OUTP + c0 + r)) * HW + n;
                float val = av[r] * sc[r] + sh[r] + res[r];
                out[oidx] = fmaxf(val, 0.f);
            }
        }
    }
}

// ---------------------------------------------------------------------------
extern "C" void kernel_launch(void* const* d_in, const int* in_sizes, int n_in,
                              void* d_out, int out_size, void* d_ws, size_t ws_size,
                              hipStream_t stream) {
    const float* x    = (const float*)d_in[0];
    const float* w1   = (const float*)d_in[1];
    const float* w2   = (const float*)d_in[2];
    const float* w3   = (const float*)d_in[3];
    const float* r1_w = (const float*)d_in[4];
    const float* r1_b = (const float*)d_in[5];
    const float* r2_w = (const float*)d_in[6];
    const float* r2_b = (const float*)d_in[7];
    const float* r3_w = (const float*)d_in[8];
    const float* r3_b = (const float*)d_in[9];
    const float* bn1_g = (const float*)d_in[10];
    const float* bn1_b = (const float*)d_in[11];
    const float* bn1_m = (const float*)d_in[12];
    const float* bn1_v = (const float*)d_in[13];
    const float* bn2_g = (const float*)d_in[14];
    const float* bn2_b = (const float*)d_in[15];
    const float* bn2_m = (const float*)d_in[16];
    const float* bn2_v = (const float*)d_in[17];
    const float* bn3_g = (const float*)d_in[18];
    const float* bn3_b = (const float*)d_in[19];
    const float* bn3_m = (const float*)d_in[20];
    const float* bn3_v = (const float*)d_in[21];
    float* out = (float*)d_out;

    // Workspace (~86.4 MB). cwX slot time-shared: cw1 (stage 1) then cw3
    // (stage 3; cw1 dead after gemm1). xb persists to gemm3 (bf16 residual).
    char* ws = (char*)d_ws;
    size_t off = 0;
    float* mean1 = (float*)(ws + off); off += (size_t)BB * INP * 4;
    float* msum2 = (float*)(ws + off); off += (size_t)BB * 256 * 4;
    float* msum3 = (float*)(ws + off); off += (size_t)BB * 256 * 4;
    unsigned short* zpad = (unsigned short*)(ws + off); off += 256;
    off = (off + 255) & ~(size_t)255;
    unsigned short* act1 = (unsigned short*)(ws + off); off += (size_t)BB * 14 * 8 * 512 * 2;  // 3.67 MB
    unsigned short* act2 = (unsigned short*)(ws + off); off += (size_t)BB * 14 * 8 * 512 * 2;  // 3.67 MB
    unsigned short* cw2 = (unsigned short*)(ws + off); off += (size_t)BB * 16 * 72 * 512 * 2;  // 37.75 MB
    unsigned short* xb  = (unsigned short*)(ws + off); off += (size_t)BB * 14 * 32 * 512 * 2;  // 14.68 MB
    unsigned short* wb2 = (unsigned short*)(ws + off); off += (size_t)S2 * NE * 2;             // 9.44 MB
    unsigned short* cwX = (unsigned short*)(ws + off); off += (size_t)BB * S1 * 2;             // 16.78 MB
    unsigned short* cw1 = cwX;
    unsigned short* cw3 = cwX;
    (void)ws_size;

    // Pre: transpose+mean of x (blocks 0-255) || permute w2 + zero
    // msum2/msum3/zpad (blocks 256-2303). Memset dispatch eliminated.
    pre_kernel<<<2304, 256, 0, stream>>>(x, xb, mean1, w2, wb2, zpad, msum2, msum3);

    // Stage 1: 1x1 conv 1024->256
    combine_cont_r<<<dim3(128, 4), 256, 0, stream>>>(w1, mean1, r1_w, r1_b, 1.0f, INP,
                                                     cw1, S1, 16, 32);
    gemm1_fused<<<dim3(BB, 4, 4), 512, 0, stream>>>(xb, cw1, bn1_g, bn1_b, bn1_m, bn1_v,
                                                    act1, msum2);

    // Stage 2: 3x3 conv 256->256
    combine_w2_r<<<dim3(288, 4), 256, 0, stream>>>(wb2, msum2, r2_w, r2_b,
                                                   1.0f / (float)HW, cw2);
    gemm2_fused<<<dim3(BB, 4, 4), 512, 0, stream>>>(act1, cw2, zpad, bn2_g, bn2_b,
                                                    bn2_m, bn2_v, act2, msum3);

    // Stage 3: 1x1 conv 256->1024 + residual
    combine_cont_r<<<dim3(128, 4), 256, 0, stream>>>(w3, msum3, r3_w, r3_b,
                                                     1.0f / (float)HW, WIDTH,
                                                     cw3, S3, 64, 8);
    gemm3_fused<<<dim3(BB, 16), 512, 0, stream>>>(act2, cw3, bn3_g, bn3_b, bn3_m, bn3_v,
                                                  xb, out);
}

// Round 7
// 238.962 us; speedup vs baseline: 1.2158x; 1.0078x over previous
//
#include <hip/hip_runtime.h>
#include <hip/hip_bf16.h>
#include <hip/hip_cooperative_groups.h>

namespace cg = cooperative_groups;

#define BB 32
#define INP 1024
#define WIDTH 256
#define OUTP 1024
#define NE 8
#define HW 196
#define HH 14
#define EPS 1e-5f

#define S1 (WIDTH * INP)        // 262144
#define S2 (WIDTH * WIDTH * 9)  // 589824
#define S3 (OUTP * WIDTH)       // 262144

typedef __attribute__((ext_vector_type(8))) short bf16x8;
typedef __attribute__((ext_vector_type(4))) float f32x4;
typedef __attribute__((ext_vector_type(8))) unsigned short u16x8;

// Swizzled operand layout: tile = 16 rows x 32 k = 512 bf16 = 1 KB.
// Element (r,k) at lane*8 + (k&7), lane = (r&15) | (((k>>3)&3)<<4).

#define VMCNT(n) asm volatile("s_waitcnt vmcnt(" #n ")" ::: "memory")

__device__ __forceinline__ unsigned short f2bf_bits(float f) {
    unsigned u = __float_as_uint(f);
    u += 0x7FFFu + ((u >> 16) & 1u);   // RNE
    return (unsigned short)(u >> 16);
}
__device__ __forceinline__ float bf2f(unsigned short h) {
    return __uint_as_float((unsigned)h << 16);
}

#if defined(__has_builtin)
#if __has_builtin(__builtin_amdgcn_global_load_lds)
#define HAVE_GLL 1
#endif
#endif
__device__ __forceinline__ void gl2lds(const unsigned short* g, unsigned short* l,
                                       int lane) {
#ifdef HAVE_GLL
    __builtin_amdgcn_global_load_lds(
        (const __attribute__((address_space(1))) unsigned int*)(const void*)g,
        (__attribute__((address_space(3))) unsigned int*)(void*)l, 16, 0, 0);
#else
    *(u16x8*)(l + lane * 8) = *(const u16x8*)g;
#endif
}

// ===========================================================================
// ======================= MULTI-KERNEL PATH (round-5, known-good) ===========
// ===========================================================================

// ---------------------------------------------------------------------------
// In-block routing (8-sample group g): srw[s*8+e] = sigmoid(scale*(v@W)+b).
// ---------------------------------------------------------------------------
__device__ __forceinline__ void block_route(
    const float* __restrict__ vec, const float* __restrict__ W,
    const float* __restrict__ bias, float scale, int C, int g,
    float* srw, int tid) {
    int wv = tid >> 6, lane = tid & 63;
    float p0[NE], p1[NE];
#pragma unroll
    for (int e = 0; e < NE; e++) { p0[e] = 0.f; p1[e] = 0.f; }
    const float* v0 = vec + (size_t)(g * 8 + wv * 2) * C;
    const float* v1 = v0 + C;
    for (int c = lane; c < C; c += 64) {
        float4 wa = *(const float4*)(W + c * 8);
        float4 wb = *(const float4*)(W + c * 8 + 4);
        float m0 = v0[c], m1 = v1[c];
        p0[0] += m0 * wa.x; p0[1] += m0 * wa.y; p0[2] += m0 * wa.z; p0[3] += m0 * wa.w;
        p0[4] += m0 * wb.x; p0[5] += m0 * wb.y; p0[6] += m0 * wb.z; p0[7] += m0 * wb.w;
        p1[0] += m1 * wa.x; p1[1] += m1 * wa.y; p1[2] += m1 * wa.z; p1[3] += m1 * wa.w;
        p1[4] += m1 * wb.x; p1[5] += m1 * wb.y; p1[6] += m1 * wb.z; p1[7] += m1 * wb.w;
    }
#pragma unroll
    for (int j = 1; j < 64; j <<= 1) {
#pragma unroll
        for (int e = 0; e < NE; e++) {
            p0[e] += __shfl_xor(p0[e], j, 64);
            p1[e] += __shfl_xor(p1[e], j, 64);
        }
    }
    if (lane == 0) {
#pragma unroll
        for (int e = 0; e < NE; e++) {
            srw[(wv * 2) * 8 + e] = 1.0f / (1.0f + expf(-(scale * p0[e] + bias[e])));
            srw[(wv * 2 + 1) * 8 + e] = 1.0f / (1.0f + expf(-(scale * p1[e] + bias[e])));
        }
    }
    __syncthreads();
}

// ---------------------------------------------------------------------------
// Merged pre-kernel (also zeroes msum2/msum3/zpad).
// ---------------------------------------------------------------------------
__global__ __launch_bounds__(256) void pre_kernel(
    const float* __restrict__ x, unsigned short* __restrict__ xb,
    float* __restrict__ mean1,
    const float* __restrict__ w2, unsigned short* __restrict__ wb2,
    unsigned short* __restrict__ zpad,
    float* __restrict__ msum2, float* __restrict__ msum3) {
    __shared__ __align__(16) char smem[128 * 17 * 4];
    int blk = blockIdx.x, t = threadIdx.x;
    if (blk < 256) {
        float (*lt)[17] = (float(*)[17])smem;
        int b = blk >> 3, yq = blk & 7, c0 = yq * 128;
        int cr = t >> 1, half = t & 1;
        const float* src = x + ((size_t)(b * INP + c0 + cr)) * HW;
        float msum = 0.f;
        int j = t >> 4, nl = t & 15;
        for (int pg = 0; pg < 14; pg++) {
            int p0 = pg * 16 + half * 8;
            float vv[8];
            if (pg < 12) {
                float4 a = *(const float4*)(src + p0);
                float4 c = *(const float4*)(src + p0 + 4);
                vv[0] = a.x; vv[1] = a.y; vv[2] = a.z; vv[3] = a.w;
                vv[4] = c.x; vv[5] = c.y; vv[6] = c.z; vv[7] = c.w;
            } else {
#pragma unroll
                for (int i = 0; i < 8; i++) {
                    int p = p0 + i;
                    vv[i] = (p < HW) ? src[p] : 0.f;
                }
            }
#pragma unroll
            for (int i = 0; i < 8; i++) { msum += vv[i]; lt[cr][half * 8 + i] = vv[i]; }
            __syncthreads();
            unsigned short pk[8];
#pragma unroll
            for (int i = 0; i < 8; i++) pk[i] = f2bf_bits(lt[j * 8 + i][nl]);
            size_t tile = ((size_t)b * 14 + pg) * 32 + (size_t)(yq * 4 + (j >> 2));
            int lane = nl | ((j & 3) << 4);
            *(u16x8*)(xb + tile * 512 + lane * 8) = *(u16x8*)pk;
            __syncthreads();
        }
        float other = __shfl_xor(msum, 1, 64);
        if (half == 0) mean1[b * INP + c0 + cr] = (msum + other) * (1.0f / (float)HW);
    } else {
        unsigned short* lds = (unsigned short*)smem;
        int eo = blk - 256;
        if (eo < 32) {
            int idx = eo * 256 + t;
            msum2[idx] = 0.f;
            msum3[idx] = 0.f;
            if (eo == 0 && t == 0) {
                u16x8 z = {0, 0, 0, 0, 0, 0, 0, 0};
                *(u16x8*)zpad = z;
            }
        }
        const float* src = w2 + (size_t)eo * 2304 + (size_t)t * 9;
#pragma unroll
        for (int t9 = 0; t9 < 9; t9++) lds[t9 * 256 + t] = f2bf_bits(src[t9]);
        __syncthreads();
        unsigned short* dst = wb2 + (size_t)eo * 2304;
        for (int j = t; j < 288; j += 256)
            *(u16x8*)(dst + j * 8) = *(const u16x8*)(lds + j * 8);
    }
}

// ---------------------------------------------------------------------------
// Combine (contiguous-k fp32 experts, w1/w3) + fused routing.
// ---------------------------------------------------------------------------
__global__ __launch_bounds__(256) void combine_cont_r(
    const float* __restrict__ w, const float* __restrict__ vec,
    const float* __restrict__ rW, const float* __restrict__ rB, float scale, int C,
    unsigned short* __restrict__ cw, int S, int Mt, int Kt) {
    __shared__ float srw[64];
    int tid = threadIdx.x, wv = tid >> 6, lane = tid & 63, ml = lane & 15, k8l = lane >> 4;
    int g = blockIdx.y;
    block_route(vec, rW, rB, scale, C, g, srw, tid);
    int kq = Kt >> 2;
    int mt = blockIdx.x / kq, kt = (blockIdx.x - mt * kq) * 4 + wv;
    int K = Kt * 32;
    const float* src = w + (size_t)(mt * 16 + ml) * K + kt * 32 + k8l * 8;
    float v[NE][8];
#pragma unroll
    for (int e = 0; e < NE; e++) {
        float4 a = *(const float4*)(src + (size_t)e * S);
        float4 c = *(const float4*)(src + (size_t)e * S + 4);
        v[e][0] = a.x; v[e][1] = a.y; v[e][2] = a.z; v[e][3] = a.w;
        v[e][4] = c.x; v[e][5] = c.y; v[e][6] = c.z; v[e][7] = c.w;
    }
    size_t dto = ((size_t)mt * Kt + kt) * 512 + (size_t)lane * 8;
    size_t bstr = (size_t)Mt * Kt * 512;
    for (int bl = 0; bl < 8; bl++) {
        int b = g * 8 + bl;
        float acc[8];
#pragma unroll
        for (int jj = 0; jj < 8; jj++) acc[jj] = 0.f;
#pragma unroll
        for (int e = 0; e < NE; e++) {
            float r = srw[bl * NE + e];
#pragma unroll
            for (int jj = 0; jj < 8; jj++) acc[jj] += r * v[e][jj];
        }
        u16x8 o;
#pragma unroll
        for (int jj = 0; jj < 8; jj++) o[jj] = f2bf_bits(acc[jj]);
        *(u16x8*)(cw + (size_t)b * bstr + dto) = o;
    }
}

// ---------------------------------------------------------------------------
// Combine w2 (k-ordered bf16 wb2) + fused routing. grid = (288, 4 groups).
// ---------------------------------------------------------------------------
__global__ __launch_bounds__(256) void combine_w2_r(
    const unsigned short* __restrict__ wb2, const float* __restrict__ vec,
    const float* __restrict__ rW, const float* __restrict__ rB, float scale,
    unsigned short* __restrict__ cw) {
    __shared__ float srw[64];
    int tid = threadIdx.x, wv = tid >> 6, lane = tid & 63, ol = lane & 15, g4 = lane >> 4;
    int g = blockIdx.y;
    block_route(vec, rW, rB, scale, 256, g, srw, tid);
    int ot = blockIdx.x / 18, kt = (blockIdx.x - ot * 18) * 4 + wv;
    const unsigned short* src = wb2 + (size_t)(ot * 16 + ol) * 2304 + kt * 32 + g4 * 8;
    float v[NE][8];
#pragma unroll
    for (int e = 0; e < NE; e++) {
        u16x8 raw = *(const u16x8*)(src + (size_t)e * S2);
#pragma unroll
        for (int jj = 0; jj < 8; jj++) v[e][jj] = bf2f(raw[jj]);
    }
    size_t dto = ((size_t)ot * 72 + kt) * 512 + (size_t)lane * 8;
    for (int bl = 0; bl < 8; bl++) {
        int b = g * 8 + bl;
        float acc[8];
#pragma unroll
        for (int jj = 0; jj < 8; jj++) acc[jj] = 0.f;
#pragma unroll
        for (int e = 0; e < NE; e++) {
            float r = srw[bl * NE + e];
#pragma unroll
            for (int jj = 0; jj < 8; jj++) acc[jj] += r * v[e][jj];
        }
        u16x8 out;
#pragma unroll
        for (int jj = 0; jj < 8; jj++) out[jj] = f2bf_bits(acc[jj]);
        *(u16x8*)(cw + (size_t)b * (16 * 72 * 512) + dto) = out;
    }
}

// ---------------------------------------------------------------------------
// Fused epilogue: BN + ReLU -> swizzled bf16 act + per-channel sum atomics.
// ---------------------------------------------------------------------------
__device__ __forceinline__ void epilogue_act(
    const f32x4* acc, int b, int mt, int nt0, int nB, int lo, int g4,
    const float* __restrict__ g, const float* __restrict__ be,
    const float* __restrict__ mu, const float* __restrict__ var,
    unsigned short* __restrict__ actout, float* __restrict__ msum) {
    int c0 = mt * 16 + g4 * 4;
    float sc[4], sh[4];
#pragma unroll
    for (int r = 0; r < 4; r++) {
        float iv = rsqrtf(var[c0 + r] + EPS) * g[c0 + r];
        sc[r] = iv;
        sh[r] = be[c0 + r] - mu[c0 + r] * iv;
    }
    float ms[4] = {0.f, 0.f, 0.f, 0.f};
    int ktc = mt >> 1;
    int lanehi = ((mt * 2 + (g4 >> 1)) & 3) << 4;
#pragma unroll
    for (int t = 0; t < 4; t++) {
        if (t >= nB) break;
        int nt = nt0 + t;
        int n = nt * 16 + lo;
        float v[4];
#pragma unroll
        for (int r = 0; r < 4; r++) {
            float val = acc[t][r] * sc[r] + sh[r];
            val = fmaxf(val, 0.f);
            if (n >= HW) val = 0.f;
            v[r] = val;
            ms[r] += val;
        }
        unsigned p01 = (unsigned)f2bf_bits(v[0]) | ((unsigned)f2bf_bits(v[1]) << 16);
        unsigned p23 = (unsigned)f2bf_bits(v[2]) | ((unsigned)f2bf_bits(v[3]) << 16);
        size_t off = (((size_t)(b * 14 + nt)) * 8 + ktc) * 512 + (size_t)(lo | lanehi) * 8 + (g4 & 1) * 4;
        *(uint2*)(actout + off) = make_uint2(p01, p23);
    }
#pragma unroll
    for (int r = 0; r < 4; r++) {
        float s = ms[r];
        s += __shfl_xor(s, 1, 64);
        s += __shfl_xor(s, 2, 64);
        s += __shfl_xor(s, 4, 64);
        s += __shfl_xor(s, 8, 64);
        if (lo == 0) atomicAdd(&msum[b * 256 + c0 + r], s);
    }
}

// ---------------------------------------------------------------------------
// Stage-1 fused GEMM (round-5 form): (BB,4,4), 8-buffer counted-vmcnt.
// ---------------------------------------------------------------------------
__global__ __launch_bounds__(512) void gemm1_fused(
    const unsigned short* __restrict__ Bsw, const unsigned short* __restrict__ Asw,
    const float* __restrict__ g, const float* __restrict__ be,
    const float* __restrict__ mu, const float* __restrict__ var,
    unsigned short* __restrict__ actout, float* __restrict__ msum) {
    __shared__ __align__(16) unsigned short lAb[8][4 * 512];
    __shared__ __align__(16) unsigned short lBb[8][4 * 512];
    const int Kt = 32;
    int b = blockIdx.x, mh = blockIdx.y, z = blockIdx.z;
    int nt0 = (z < 3) ? z * 4 : 11;
    int nB = (z < 2) ? 4 : 3;
    int tid = threadIdx.x, wv = tid >> 6, grp = wv >> 2, wl = wv & 3;
    int lane = tid & 63, lo = lane & 15, g4 = lane >> 4;
    const unsigned short* Ab = Asw + (size_t)(b * 16 + mh * 4) * Kt * 512;
    const unsigned short* Bb = Bsw + (size_t)(b * 14 + nt0) * Kt * 512;
    f32x4 acc[4];
#pragma unroll
    for (int t = 0; t < 4; t++) acc[t] = {0.f, 0.f, 0.f, 0.f};

    auto stage = [&](int kt) {
        unsigned short* lA = lAb[kt & 7];
        unsigned short* lB = lBb[kt & 7];
        gl2lds(Ab + ((size_t)wl * Kt + kt) * 512 + lane * 8, lA + wl * 512, lane);
        if (wl < nB)
            gl2lds(Bb + ((size_t)wl * Kt + kt) * 512 + lane * 8, lB + wl * 512, lane);
    };
    auto compute = [&](int kt) {
        const unsigned short* lA = lAb[kt & 7];
        const unsigned short* lB = lBb[kt & 7];
        bf16x8 a0 = *(const bf16x8*)(lA + wl * 512 + lane * 8);
#pragma unroll
        for (int t = 0; t < 4; t++) {
            if (t >= nB) break;
            bf16x8 bt = *(const bf16x8*)(lB + t * 512 + lane * 8);
            acc[t] = __builtin_amdgcn_mfma_f32_16x16x32_bf16(a0, bt, acc[t], 0, 0, 0);
        }
    };

    stage(grp);
    stage(grp + 2);
    for (int kp = 0; kp < 16; kp++) {
        int c = 2 * kp + grp;
        if (c + 2 < 32) {
            if (wl < nB) VMCNT(2); else VMCNT(1);
        } else {
            VMCNT(0);
        }
        __builtin_amdgcn_s_barrier();
        int s = c + 4;
        if (s < 32) stage(s);
        compute(c);
    }
    __syncthreads();
    float* red = (float*)&lBb[0][0];
    if (grp == 1) {
#pragma unroll
        for (int t = 0; t < 4; t++)
            *(f32x4*)(red + (((size_t)wl * 4 + t) * 64 + lane) * 4) = acc[t];
    }
    __syncthreads();
    if (grp == 0) {
#pragma unroll
        for (int t = 0; t < 4; t++) {
            f32x4 o = *(const f32x4*)(red + (((size_t)wl * 4 + t) * 64 + lane) * 4);
#pragma unroll
            for (int r = 0; r < 4; r++) acc[t][r] += o[r];
        }
        epilogue_act(acc, b, mh * 4 + wl, nt0, nB, lo, g4, g, be, mu, var, actout, msum);
    }
}

// ---------------------------------------------------------------------------
// Stage-2 fused GEMM (round-5 form): (BB,4,4), 8-buffer counted-vmcnt.
// ---------------------------------------------------------------------------
__global__ __launch_bounds__(512) void gemm2_fused(
    const unsigned short* __restrict__ act, const unsigned short* __restrict__ cw2,
    const unsigned short* __restrict__ zpad,
    const float* __restrict__ g, const float* __restrict__ be,
    const float* __restrict__ mu, const float* __restrict__ var,
    unsigned short* __restrict__ actout, float* __restrict__ msum) {
    __shared__ __align__(16) unsigned short lAb[8][4 * 512];
    __shared__ __align__(16) unsigned short lBb[8][4 * 512];
    int b = blockIdx.x, mh = blockIdx.y, z = blockIdx.z;
    int nt0 = (z < 3) ? z * 4 : 11;
    int nB = (z < 2) ? 4 : 3;
    int tid = threadIdx.x, wv = tid >> 6, grp = wv >> 2, wl = wv & 3;
    int lane = tid & 63, lo = lane & 15, g4 = lane >> 4;
    const unsigned short* Ab = cw2 + (size_t)(b * 16 + mh * 4) * 72 * 512;
    const unsigned short* actb = act + (size_t)b * 14 * 8 * 512;

    int p0 = (nt0 + wl) * 16 + lo;
    int py0 = p0 / HH, px0 = p0 - (p0 / HH) * HH;
    bool pv0 = (wl < nB) && (p0 < HW);

    f32x4 acc[4];
#pragma unroll
    for (int t = 0; t < 4; t++) acc[t] = {0.f, 0.f, 0.f, 0.f};

    auto stage = [&](int kt) {
        unsigned short* lA = lAb[kt & 7];
        unsigned short* lB = lBb[kt & 7];
        gl2lds(Ab + ((size_t)wl * 72 + kt) * 512 + lane * 8, lA + wl * 512, lane);
        if (wl < nB) {
            int t9 = kt >> 3;
            int dy = t9 / 3 - 1, dx = t9 - (t9 / 3) * 3 - 1;
            int itile = kt & 7;
            int sy = py0 + dy, sx = px0 + dx;
            bool ok = pv0 && sy >= 0 && sy < HH && sx >= 0 && sx < HH;
            int ns = sy * HH + sx;
            const unsigned short* gp = ok
                ? actb + ((size_t)(ns >> 4) * 8 + itile) * 512 + (size_t)((ns & 15) | (g4 << 4)) * 8
                : zpad;
            gl2lds(gp, lB + wl * 512, lane);
        }
    };
    auto compute = [&](int kt) {
        const unsigned short* lA = lAb[kt & 7];
        const unsigned short* lB = lBb[kt & 7];
        bf16x8 a0 = *(const bf16x8*)(lA + wl * 512 + lane * 8);
#pragma unroll
        for (int t = 0; t < 4; t++) {
            if (t >= nB) break;
            bf16x8 bt = *(const bf16x8*)(lB + t * 512 + lane * 8);
            acc[t] = __builtin_amdgcn_mfma_f32_16x16x32_bf16(a0, bt, acc[t], 0, 0, 0);
        }
    };

    stage(grp);
    stage(grp + 2);
    for (int kp = 0; kp < 36; kp++) {
        int c = 2 * kp + grp;
        if (c + 2 < 72) {
            if (wl < nB) VMCNT(2); else VMCNT(1);
        } else {
            VMCNT(0);
        }
        __builtin_amdgcn_s_barrier();
        int s = c + 4;
        if (s < 72) stage(s);
        compute(c);
    }
    __syncthreads();
    float* red = (float*)&lBb[0][0];
    if (grp == 1) {
#pragma unroll
        for (int t = 0; t < 4; t++)
            *(f32x4*)(red + (((size_t)wl * 4 + t) * 64 + lane) * 4) = acc[t];
    }
    __syncthreads();
    if (grp == 0) {
#pragma unroll
        for (int t = 0; t < 4; t++) {
            f32x4 o = *(const f32x4*)(red + (((size_t)wl * 4 + t) * 64 + lane) * 4);
#pragma unroll
            for (int r = 0; r < 4; r++) acc[t][r] += o[r];
        }
        epilogue_act(acc, b, mh * 4 + wl, nt0, nB, lo, g4, g, be, mu, var, actout, msum);
    }
}

// ---------------------------------------------------------------------------
// Stage-3 GEMM (round-5 form): (BB,16), 4-buffer, BN + residual + ReLU.
// ---------------------------------------------------------------------------
__global__ __launch_bounds__(512) void gemm3_fused(
    const unsigned short* __restrict__ Bsw, const unsigned short* __restrict__ Asw,
    const float* __restrict__ g, const float* __restrict__ be,
    const float* __restrict__ mu, const float* __restrict__ var,
    const unsigned short* __restrict__ xb, float* __restrict__ out) {
    __shared__ __align__(16) unsigned short lAb[4][8 * 512];
    __shared__ __align__(16) unsigned short lBb[4][7 * 512];
    int b = blockIdx.x, y = blockIdx.y, mh = y >> 1, nh = y & 1;
    int tid = threadIdx.x, wv = tid >> 6, grp = wv >> 2, wl = wv & 3;
    int lane = tid & 63, lo = lane & 15, g4 = lane >> 4;
    const unsigned short* Ab = Asw + (size_t)(b * 64 + mh * 8) * 8 * 512;
    const unsigned short* Bb = Bsw + (size_t)(b * 14 + nh * 7) * 8 * 512;
    f32x4 acc0[7], acc1[7];
#pragma unroll
    for (int t = 0; t < 7; t++) { acc0[t] = {0.f, 0.f, 0.f, 0.f}; acc1[t] = {0.f, 0.f, 0.f, 0.f}; }

    auto stage = [&](int kt, unsigned short* lA, unsigned short* lB) {
        gl2lds(Ab + ((size_t)wl * 8 + kt) * 512 + lane * 8, lA + wl * 512, lane);
        gl2lds(Ab + ((size_t)(wl + 4) * 8 + kt) * 512 + lane * 8, lA + (wl + 4) * 512, lane);
        gl2lds(Bb + ((size_t)wl * 8 + kt) * 512 + lane * 8, lB + wl * 512, lane);
        if (wl < 3)
            gl2lds(Bb + ((size_t)(4 + wl) * 8 + kt) * 512 + lane * 8, lB + (4 + wl) * 512, lane);
    };
    auto compute = [&](const unsigned short* lA, const unsigned short* lB) {
        bf16x8 a0 = *(const bf16x8*)(lA + wl * 512 + lane * 8);
        bf16x8 a1 = *(const bf16x8*)(lA + (wl + 4) * 512 + lane * 8);
#pragma unroll
        for (int t = 0; t < 7; t++) {
            bf16x8 bt = *(const bf16x8*)(lB + t * 512 + lane * 8);
            acc0[t] = __builtin_amdgcn_mfma_f32_16x16x32_bf16(a0, bt, acc0[t], 0, 0, 0);
            acc1[t] = __builtin_amdgcn_mfma_f32_16x16x32_bf16(a1, bt, acc1[t], 0, 0, 0);
        }
    };

    stage(grp, lAb[grp], lBb[grp]);
    for (int kp = 0; kp < 4; kp++) {
        __syncthreads();
        if (kp < 3) {
            int s = 2 * kp + 2 + grp;
            stage(s, lAb[s & 3], lBb[s & 3]);
        }
        int c = (2 * kp + grp) & 3;
        compute(lAb[c], lBb[c]);
    }
    __syncthreads();
    float* red = (float*)&lBb[0][0];
    if (grp == 1) {
#pragma unroll
        for (int t = 0; t < 7; t++)
            *(f32x4*)(red + (((size_t)wl * 7 + t) * 64 + lane) * 4) = acc0[t];
    }
    __syncthreads();
    if (grp == 0) {
#pragma unroll
        for (int t = 0; t < 7; t++) {
            f32x4 o = *(const f32x4*)(red + (((size_t)wl * 7 + t) * 64 + lane) * 4);
#pragma unroll
            for (int r = 0; r < 4; r++) acc0[t][r] += o[r];
        }
    }
    __syncthreads();
    if (grp == 1) {
#pragma unroll
        for (int t = 0; t < 7; t++)
            *(f32x4*)(red + (((size_t)wl * 7 + t) * 64 + lane) * 4) = acc1[t];
    }
    __syncthreads();
    if (grp != 0) return;
#pragma unroll
    for (int t = 0; t < 7; t++) {
        f32x4 o = *(const f32x4*)(red + (((size_t)wl * 7 + t) * 64 + lane) * 4);
#pragma unroll
        for (int r = 0; r < 4; r++) acc1[t][r] += o[r];
    }

#pragma unroll
    for (int a = 0; a < 2; a++) {
        int mt = mh * 8 + wl + 4 * a;
        int c0 = mt * 16 + g4 * 4;
        float sc[4], sh[4];
#pragma unroll
        for (int r = 0; r < 4; r++) {
            float iv = rsqrtf(var[c0 + r] + EPS) * g[c0 + r];
            sc[r] = iv;
            sh[r] = be[c0 + r] - mu[c0 + r] * iv;
        }
        int ktc = mt >> 1;
        int lanehi = ((mt * 2 + (g4 >> 1)) & 3) << 4;
#pragma unroll
        for (int t = 0; t < 7; t++) {
            int nt = nh * 7 + t;
            int n = nt * 16 + lo;
            if (n >= HW) continue;
            const unsigned short* xr = xb + (((size_t)(b * 14 + nt)) * 32 + ktc) * 512
                                       + (size_t)(lo | lanehi) * 8 + (g4 & 1) * 4;
            uint2 rv = *(const uint2*)xr;
            float res[4] = {bf2f((unsigned short)(rv.x & 0xffff)),
                            bf2f((unsigned short)(rv.x >> 16)),
                            bf2f((unsigned short)(rv.y & 0xffff)),
                            bf2f((unsigned short)(rv.y >> 16))};
            f32x4 av = a ? acc1[t] : acc0[t];
#pragma unroll
            for (int r = 0; r < 4; r++) {
                size_t oidx = ((size_t)(b * OUTP + c0 + r)) * HW + n;
                float val = av[r] * sc[r] + sh[r] + res[r];
                out[oidx] = fmaxf(val, 0.f);
            }
        }
    }
}

// ===========================================================================
// ============================ MEGA-KERNEL PATH =============================
// (only used when NOT stream-capturing and cooperative occupancy validates)
// ===========================================================================

struct MegaP {
    const float *x, *w1, *w2, *w3;
    const float *r1w, *r1b, *r2w, *r2b, *r3w, *r3b;
    const float *bn1g, *bn1b, *bn1m, *bn1v;
    const float *bn2g, *bn2b, *bn2m, *bn2v;
    const float *bn3g, *bn3b, *bn3m, *bn3v;
    float* out;
    float *mean1, *msum2, *msum3;
    unsigned short *zpad, *act1, *act2, *cw2, *xb, *wb2, *cwX;
};

__device__ __forceinline__ void route512(
    const float* vec, const float* W, const float* bias, float scale, int C,
    int g, float* srw, int tid) {
    int wv = tid >> 6, lane = tid & 63;
    float pp[NE];
#pragma unroll
    for (int e = 0; e < NE; e++) pp[e] = 0.f;
    const float* v0 = vec + (size_t)(g * 8 + wv) * C;
    for (int c = lane; c < C; c += 64) {
        float4 wa = *(const float4*)(W + c * 8);
        float4 wb = *(const float4*)(W + c * 8 + 4);
        float m = v0[c];
        pp[0] += m * wa.x; pp[1] += m * wa.y; pp[2] += m * wa.z; pp[3] += m * wa.w;
        pp[4] += m * wb.x; pp[5] += m * wb.y; pp[6] += m * wb.z; pp[7] += m * wb.w;
    }
#pragma unroll
    for (int j = 1; j < 64; j <<= 1) {
#pragma unroll
        for (int e = 0; e < NE; e++) pp[e] += __shfl_xor(pp[e], j, 64);
    }
    if (lane == 0) {
#pragma unroll
        for (int e = 0; e < NE; e++)
            srw[wv * 8 + e] = 1.0f / (1.0f + expf(-(scale * pp[e] + bias[e])));
    }
    __syncthreads();
}

__device__ __forceinline__ void phase_pre(const MegaP& p, char* smem, int r, int tid) {
    if (r < 256) {
        float (*lt)[17] = (float(*)[17])smem;
        bool act = tid < 256;
        int b = r >> 3, yq = r & 7, c0 = yq * 128;
        int cr = tid >> 1, half = tid & 1;
        const float* src = act ? p.x + ((size_t)(b * INP + c0 + cr)) * HW : p.x;
        float msum = 0.f;
        int j = tid >> 4, nl = tid & 15;
        for (int pg = 0; pg < 14; pg++) {
            if (act) {
                int p0 = pg * 16 + half * 8;
                float vv[8];
                if (pg < 12) {
                    float4 a = *(const float4*)(src + p0);
                    float4 c = *(const float4*)(src + p0 + 4);
                    vv[0] = a.x; vv[1] = a.y; vv[2] = a.z; vv[3] = a.w;
                    vv[4] = c.x; vv[5] = c.y; vv[6] = c.z; vv[7] = c.w;
                } else {
#pragma unroll
                    for (int i = 0; i < 8; i++) {
                        int pp = p0 + i;
                        vv[i] = (pp < HW) ? src[pp] : 0.f;
                    }
                }
#pragma unroll
                for (int i = 0; i < 8; i++) { msum += vv[i]; lt[cr][half * 8 + i] = vv[i]; }
            }
            __syncthreads();
            if (act) {
                unsigned short pk[8];
#pragma unroll
                for (int i = 0; i < 8; i++) pk[i] = f2bf_bits(lt[j * 8 + i][nl]);
                size_t tile = ((size_t)b * 14 + pg) * 32 + (size_t)(yq * 4 + (j >> 2));
                int lane = nl | ((j & 3) << 4);
                *(u16x8*)(p.xb + tile * 512 + lane * 8) = *(u16x8*)pk;
            }
            __syncthreads();
        }
        if (act) {
            float other = __shfl_xor(msum, 1, 64);
            if (half == 0) p.mean1[b * INP + c0 + cr] = (msum + other) * (1.0f / (float)HW);
        }
    } else {
        int rb = r - 256;
        int sub = tid >> 8, vt = tid & 255;
        unsigned short* lds = (unsigned short*)smem + sub * 2304;
        if (rb < 32 && tid < 256) {
            int idx = rb * 256 + tid;
            p.msum2[idx] = 0.f;
            p.msum3[idx] = 0.f;
        }
        if (rb == 0 && tid == 0) {
            u16x8 z = {0, 0, 0, 0, 0, 0, 0, 0};
            *(u16x8*)p.zpad = z;
        }
        for (int it = 0; it < 4; it++) {
            int eo = rb * 8 + it * 2 + sub;
            const float* s2 = p.w2 + (size_t)eo * 2304 + (size_t)vt * 9;
#pragma unroll
            for (int t9 = 0; t9 < 9; t9++) lds[t9 * 256 + vt] = f2bf_bits(s2[t9]);
            __syncthreads();
            unsigned short* dst = p.wb2 + (size_t)eo * 2304;
            for (int jj = vt; jj < 288; jj += 256)
                *(u16x8*)(dst + jj * 8) = *(const u16x8*)(lds + jj * 8);
            __syncthreads();
        }
    }
}

__device__ __forceinline__ void phase_combine_cont(
    const float* w, const float* vec, const float* rW, const float* rB,
    float scale, int C, unsigned short* cw, int S, int Mt, int Kt,
    char* smem, int r, int tid) {
    if (r >= 256) return;
    float* srw = (float*)smem;
    int wv = tid >> 6, lane = tid & 63, ml = lane & 15, k8l = lane >> 4;
    int g = r & 3, xp = r >> 2;
    route512(vec, rW, rB, scale, C, g, srw, tid);
    int kq8 = Kt >> 3;
    int mt = xp / kq8, kt = (xp - mt * kq8) * 8 + wv;
    int K = Kt * 32;
    const float* src = w + (size_t)(mt * 16 + ml) * K + kt * 32 + k8l * 8;
    float v[NE][8];
#pragma unroll
    for (int e = 0; e < NE; e++) {
        float4 a = *(const float4*)(src + (size_t)e * S);
        float4 c = *(const float4*)(src + (size_t)e * S + 4);
        v[e][0] = a.x; v[e][1] = a.y; v[e][2] = a.z; v[e][3] = a.w;
        v[e][4] = c.x; v[e][5] = c.y; v[e][6] = c.z; v[e][7] = c.w;
    }
    size_t dto = ((size_t)mt * Kt + kt) * 512 + (size_t)lane * 8;
    size_t bstr = (size_t)Mt * Kt * 512;
    for (int bl = 0; bl < 8; bl++) {
        int b = g * 8 + bl;
        float acc[8];
#pragma unroll
        for (int jj = 0; jj < 8; jj++) acc[jj] = 0.f;
#pragma unroll
        for (int e = 0; e < NE; e++) {
            float rr = srw[bl * NE + e];
#pragma unroll
            for (int jj = 0; jj < 8; jj++) acc[jj] += rr * v[e][jj];
        }
        u16x8 o;
#pragma unroll
        for (int jj = 0; jj < 8; jj++) o[jj] = f2bf_bits(acc[jj]);
        *(u16x8*)(cw + (size_t)b * bstr + dto) = o;
    }
}

__device__ __forceinline__ void phase_combine_w2(const MegaP& p, char* smem,
                                                 int r, int tid) {
    float* srw = (float*)smem;
    int wv = tid >> 6, lane = tid & 63, ol = lane & 15, g4 = lane >> 4;
    int g = r & 3, u = r >> 2;
    route512(p.msum2, p.r2w, p.r2b, 1.0f / (float)HW, 256, g, srw, tid);
    for (int it = 0; it < 2; it++) {
        int bx;
        if (it == 0) bx = u + (wv >= 4 ? 128 : 0);
        else {
            if (wv >= 4 || u >= 32) break;
            bx = u + 256;
        }
        int ot = bx / 18, ktq = bx - ot * 18;
        int kt = ktq * 4 + (wv & 3);
        const unsigned short* src = p.wb2 + (size_t)(ot * 16 + ol) * 2304 + kt * 32 + g4 * 8;
        float v[NE][8];
#pragma unroll
        for (int e = 0; e < NE; e++) {
            u16x8 raw = *(const u16x8*)(src + (size_t)e * S2);
#pragma unroll
            for (int jj = 0; jj < 8; jj++) v[e][jj] = bf2f(raw[jj]);
        }
        size_t dto = ((size_t)ot * 72 + kt) * 512 + (size_t)lane * 8;
        for (int bl = 0; bl < 8; bl++) {
            int b = g * 8 + bl;
            float acc[8];
#pragma unroll
            for (int jj = 0; jj < 8; jj++) acc[jj] = 0.f;
#pragma unroll
            for (int e = 0; e < NE; e++) {
                float rr = srw[bl * NE + e];
#pragma unroll
                for (int jj = 0; jj < 8; jj++) acc[jj] += rr * v[e][jj];
            }
            u16x8 o;
#pragma unroll
            for (int jj = 0; jj < 8; jj++) o[jj] = f2bf_bits(acc[jj]);
            *(u16x8*)(p.cw2 + (size_t)b * (16 * 72 * 512) + dto) = o;
        }
    }
}

__device__ __forceinline__ void phase_gemm1(const MegaP& p, char* smem, int r, int tid) {
    unsigned short (*lAb)[4 * 512] = (unsigned short(*)[4 * 512])smem;
    unsigned short (*lBb)[4 * 512] = (unsigned short(*)[4 * 512])(smem + 32768);
    const int Kt = 32;
    int b = r >> 4, mh = (r >> 2) & 3, z = r & 3;
    int nt0 = (z < 3) ? z * 4 : 11;
    int nB = (z < 2) ? 4 : 3;
    int wv = tid >> 6, grp = wv >> 2, wl = wv & 3;
    int lane = tid & 63, lo = lane & 15, g4 = lane >> 4;
    const unsigned short* Ab = p.cwX + (size_t)(b * 16 + mh * 4) * Kt * 512;
    const unsigned short* Bb = p.xb + (size_t)(b * 14 + nt0) * Kt * 512;
    f32x4 acc[4];
#pragma unroll
    for (int t = 0; t < 4; t++) acc[t] = {0.f, 0.f, 0.f, 0.f};

    auto stage = [&](int kt) {
        unsigned short* lA = lAb[kt & 7];
        unsigned short* lB = lBb[kt & 7];
        gl2lds(Ab + ((size_t)wl * Kt + kt) * 512 + lane * 8, lA + wl * 512, lane);
        if (wl < nB)
            gl2lds(Bb + ((size_t)wl * Kt + kt) * 512 + lane * 8, lB + wl * 512, lane);
    };
    auto compute = [&](int kt) {
        const unsigned short* lA = lAb[kt & 7];
        const unsigned short* lB = lBb[kt & 7];
        bf16x8 a0 = *(const bf16x8*)(lA + wl * 512 + lane * 8);
#pragma unroll
        for (int t = 0; t < 4; t++) {
            if (t >= nB) break;
            bf16x8 bt = *(const bf16x8*)(lB + t * 512 + lane * 8);
            acc[t] = __builtin_amdgcn_mfma_f32_16x16x32_bf16(a0, bt, acc[t], 0, 0, 0);
        }
    };

    stage(grp);
    stage(grp + 2);
    for (int kp = 0; kp < 16; kp++) {
        int c = 2 * kp + grp;
        if (c + 2 < 32) {
            if (wl < nB) VMCNT(2); else VMCNT(1);
        } else {
            VMCNT(0);
        }
        __builtin_amdgcn_s_barrier();
        int s = c + 4;
        if (s < 32) stage(s);
        compute(c);
    }
    __syncthreads();
    float* red = (float*)&lBb[0][0];
    if (grp == 1) {
#pragma unroll
        for (int t = 0; t < 4; t++)
            *(f32x4*)(red + (((size_t)wl * 4 + t) * 64 + lane) * 4) = acc[t];
    }
    __syncthreads();
    if (grp == 0) {
#pragma unroll
        for (int t = 0; t < 4; t++) {
            f32x4 o = *(const f32x4*)(red + (((size_t)wl * 4 + t) * 64 + lane) * 4);
#pragma unroll
            for (int rr = 0; rr < 4; rr++) acc[t][rr] += o[rr];
        }
        epilogue_act(acc, b, mh * 4 + wl, nt0, nB, lo, g4,
                     p.bn1g, p.bn1b, p.bn1m, p.bn1v, p.act1, p.msum2);
    }
}

__device__ __forceinline__ void phase_gemm2(const MegaP& p, char* smem, int r, int tid) {
    unsigned short (*lAb)[4 * 512] = (unsigned short(*)[4 * 512])smem;
    unsigned short (*lBb)[4 * 512] = (unsigned short(*)[4 * 512])(smem + 32768);
    int b = r >> 4, mh = (r >> 2) & 3, z = r & 3;
    int nt0 = (z < 3) ? z * 4 : 11;
    int nB = (z < 2) ? 4 : 3;
    int wv = tid >> 6, grp = wv >> 2, wl = wv & 3;
    int lane = tid & 63, lo = lane & 15, g4 = lane >> 4;
    const unsigned short* Ab = p.cw2 + (size_t)(b * 16 + mh * 4) * 72 * 512;
    const unsigned short* actb = p.act1 + (size_t)b * 14 * 8 * 512;

    int p0 = (nt0 + wl) * 16 + lo;
    int py0 = p0 / HH, px0 = p0 - (p0 / HH) * HH;
    bool pv0 = (wl < nB) && (p0 < HW);

    f32x4 acc[4];
#pragma unroll
    for (int t = 0; t < 4; t++) acc[t] = {0.f, 0.f, 0.f, 0.f};

    auto stage = [&](int kt) {
        unsigned short* lA = lAb[kt & 7];
        unsigned short* lB = lBb[kt & 7];
        gl2lds(Ab + ((size_t)wl * 72 + kt) * 512 + lane * 8, lA + wl * 512, lane);
        if (wl < nB) {
            int t9 = kt >> 3;
            int dy = t9 / 3 - 1, dx = t9 - (t9 / 3) * 3 - 1;
            int itile = kt & 7;
            int sy = py0 + dy, sx = px0 + dx;
            bool ok = pv0 && sy >= 0 && sy < HH && sx >= 0 && sx < HH;
            int ns = sy * HH + sx;
            const unsigned short* gp = ok
                ? actb + ((size_t)(ns >> 4) * 8 + itile) * 512 + (size_t)((ns & 15) | (g4 << 4)) * 8
                : p.zpad;
            gl2lds(gp, lB + wl * 512, lane);
        }
    };
    auto compute = [&](int kt) {
        const unsigned short* lA = lAb[kt & 7];
        const unsigned short* lB = lBb[kt & 7];
        bf16x8 a0 = *(const bf16x8*)(lA + wl * 512 + lane * 8);
#pragma unroll
        for (int t = 0; t < 4; t++) {
            if (t >= nB) break;
            bf16x8 bt = *(const bf16x8*)(lB + t * 512 + lane * 8);
            acc[t] = __builtin_amdgcn_mfma_f32_16x16x32_bf16(a0, bt, acc[t], 0, 0, 0);
        }
    };

    stage(grp);
    stage(grp + 2);
    for (int kp = 0; kp < 36; kp++) {
        int c = 2 * kp + grp;
        if (c + 2 < 72) {
            if (wl < nB) VMCNT(2); else VMCNT(1);
        } else {
            VMCNT(0);
        }
        __builtin_amdgcn_s_barrier();
        int s = c + 4;
        if (s < 72) stage(s);
        compute(c);
    }
    __syncthreads();
    float* red = (float*)&lBb[0][0];
    if (grp == 1) {
#pragma unroll
        for (int t = 0; t < 4; t++)
            *(f32x4*)(red + (((size_t)wl * 4 + t) * 64 + lane) * 4) = acc[t];
    }
    __syncthreads();
    if (grp == 0) {
#pragma unroll
        for (int t = 0; t < 4; t++) {
            f32x4 o = *(const f32x4*)(red + (((size_t)wl * 4 + t) * 64 + lane) * 4);
#pragma unroll
            for (int rr = 0; rr < 4; rr++) acc[t][rr] += o[rr];
        }
        epilogue_act(acc, b, mh * 4 + wl, nt0, nB, lo, g4,
                     p.bn2g, p.bn2b, p.bn2m, p.bn2v, p.act2, p.msum3);
    }
}

__device__ __forceinline__ void phase_gemm3(const MegaP& p, char* smem, int r, int tid) {
    unsigned short (*lAb)[8 * 512] = (unsigned short(*)[8 * 512])smem;
    unsigned short (*lBb)[7 * 512] = (unsigned short(*)[7 * 512])(smem + 32768);
    int b = r >> 4, y = r & 15, mh = y >> 1, nh = y & 1;
    int wv = tid >> 6, grp = wv >> 2, wl = wv & 3;
    int lane = tid & 63, lo = lane & 15, g4 = lane >> 4;
    const unsigned short* Ab = p.cwX + (size_t)(b * 64 + mh * 8) * 8 * 512;
    const unsigned short* Bb = p.act2 + (size_t)(b * 14 + nh * 7) * 8 * 512;
    f32x4 acc0[7], acc1[7];
#pragma unroll
    for (int t = 0; t < 7; t++) { acc0[t] = {0.f, 0.f, 0.f, 0.f}; acc1[t] = {0.f, 0.f, 0.f, 0.f}; }

    auto stage = [&](int kt, unsigned short* lA, unsigned short* lB) {
        gl2lds(Ab + ((size_t)wl * 8 + kt) * 512 + lane * 8, lA + wl * 512, lane);
        gl2lds(Ab + ((size_t)(wl + 4) * 8 + kt) * 512 + lane * 8, lA + (wl + 4) * 512, lane);
        gl2lds(Bb + ((size_t)wl * 8 + kt) * 512 + lane * 8, lB + wl * 512, lane);
        if (wl < 3)
            gl2lds(Bb + ((size_t)(4 + wl) * 8 + kt) * 512 + lane * 8, lB + (4 + wl) * 512, lane);
    };
    auto compute = [&](const unsigned short* lA, const unsigned short* lB) {
        bf16x8 a0 = *(const bf16x8*)(lA + wl * 512 + lane * 8);
        bf16x8 a1 = *(const bf16x8*)(lA + (wl + 4) * 512 + lane * 8);
#pragma unroll
        for (int t = 0; t < 7; t++) {
            bf16x8 bt = *(const bf16x8*)(lB + t * 512 + lane * 8);
            acc0[t] = __builtin_amdgcn_mfma_f32_16x16x32_bf16(a0, bt, acc0[t], 0, 0, 0);
            acc1[t] = __builtin_amdgcn_mfma_f32_16x16x32_bf16(a1, bt, acc1[t], 0, 0, 0);
        }
    };

    stage(grp, lAb[grp], lBb[grp]);
    for (int kp = 0; kp < 4; kp++) {
        __syncthreads();
        if (kp < 3) {
            int s = 2 * kp + 2 + grp;
            stage(s, lAb[s & 3], lBb[s & 3]);
        }
        int c = (2 * kp + grp) & 3;
        compute(lAb[c], lBb[c]);
    }
    __syncthreads();
    float* red = (float*)&lBb[0][0];
    if (grp == 1) {
#pragma unroll
        for (int t = 0; t < 7; t++)
            *(f32x4*)(red + (((size_t)wl * 7 + t) * 64 + lane) * 4) = acc0[t];
    }
    __syncthreads();
    if (grp == 0) {
#pragma unroll
        for (int t = 0; t < 7; t++) {
            f32x4 o = *(const f32x4*)(red + (((size_t)wl * 7 + t) * 64 + lane) * 4);
#pragma unroll
            for (int rr = 0; rr < 4; rr++) acc0[t][rr] += o[rr];
        }
    }
    __syncthreads();
    if (grp == 1) {
#pragma unroll
        for (int t = 0; t < 7; t++)
            *(f32x4*)(red + (((size_t)wl * 7 + t) * 64 + lane) * 4) = acc1[t];
    }
    __syncthreads();
    if (grp != 0) return;
#pragma unroll
    for (int t = 0; t < 7; t++) {
        f32x4 o = *(const f32x4*)(red + (((size_t)wl * 7 + t) * 64 + lane) * 4);
#pragma unroll
        for (int rr = 0; rr < 4; rr++) acc1[t][rr] += o[rr];
    }

#pragma unroll
    for (int a = 0; a < 2; a++) {
        int mt = mh * 8 + wl + 4 * a;
        int c0 = mt * 16 + g4 * 4;
        float sc[4], sh[4];
#pragma unroll
        for (int rr = 0; rr < 4; rr++) {
            float iv = rsqrtf(p.bn3v[c0 + rr] + EPS) * p.bn3g[c0 + rr];
            sc[rr] = iv;
            sh[rr] = p.bn3b[c0 + rr] - p.bn3m[c0 + rr] * iv;
        }
        int ktc = mt >> 1;
        int lanehi = ((mt * 2 + (g4 >> 1)) & 3) << 4;
#pragma unroll
        for (int t = 0; t < 7; t++) {
            int nt = nh * 7 + t;
            int n = nt * 16 + lo;
            if (n >= HW) continue;
            const unsigned short* xr = p.xb + (((size_t)(b * 14 + nt)) * 32 + ktc) * 512
                                       + (size_t)(lo | lanehi) * 8 + (g4 & 1) * 4;
            uint2 rv = *(const uint2*)xr;
            float res[4] = {bf2f((unsigned short)(rv.x & 0xffff)),
                            bf2f((unsigned short)(rv.x >> 16)),
                            bf2f((unsigned short)(rv.y & 0xffff)),
                            bf2f((unsigned short)(rv.y >> 16))};
            f32x4 av = a ? acc1[t] : acc0[t];
#pragma unroll
            for (int rr = 0; rr < 4; rr++) {
                size_t oidx = ((size_t)(b * OUTP + c0 + rr)) * HW + n;
                float val = av[rr] * sc[rr] + sh[rr] + res[rr];
                p.out[oidx] = fmaxf(val, 0.f);
            }
        }
    }
}

__global__ __launch_bounds__(512, 4) void mega_kernel(MegaP p) {
    __shared__ __align__(16) char smem[65536];
    cg::grid_group grid = cg::this_grid();
    const int r = blockIdx.x;
    const int tid = threadIdx.x;

    phase_pre(p, smem, r, tid);
    __threadfence(); grid.sync(); __threadfence();

    phase_combine_cont(p.w1, p.mean1, p.r1w, p.r1b, 1.0f, INP,
                       p.cwX, S1, 16, 32, smem, r, tid);
    __threadfence(); grid.sync(); __threadfence();

    phase_gemm1(p, smem, r, tid);
    __threadfence(); grid.sync(); __threadfence();

    phase_combine_w2(p, smem, r, tid);
    __threadfence(); grid.sync(); __threadfence();

    phase_gemm2(p, smem, r, tid);
    __threadfence(); grid.sync(); __threadfence();

    phase_combine_cont(p.w3, p.msum3, p.r3w, p.r3b, 1.0f / (float)HW, WIDTH,
                       p.cwX, S3, 64, 8, smem, r, tid);
    __threadfence(); grid.sync(); __threadfence();

    phase_gemm3(p, smem, r, tid);
}

// ---------------------------------------------------------------------------
extern "C" void kernel_launch(void* const* d_in, const int* in_sizes, int n_in,
                              void* d_out, int out_size, void* d_ws, size_t ws_size,
                              hipStream_t stream) {
    (void)in_sizes; (void)n_in; (void)out_size; (void)ws_size;
    MegaP p;
    p.x    = (const float*)d_in[0];
    p.w1   = (const float*)d_in[1];
    p.w2   = (const float*)d_in[2];
    p.w3   = (const float*)d_in[3];
    p.r1w  = (const float*)d_in[4];
    p.r1b  = (const float*)d_in[5];
    p.r2w  = (const float*)d_in[6];
    p.r2b  = (const float*)d_in[7];
    p.r3w  = (const float*)d_in[8];
    p.r3b  = (const float*)d_in[9];
    p.bn1g = (const float*)d_in[10];
    p.bn1b = (const float*)d_in[11];
    p.bn1m = (const float*)d_in[12];
    p.bn1v = (const float*)d_in[13];
    p.bn2g = (const float*)d_in[14];
    p.bn2b = (const float*)d_in[15];
    p.bn2m = (const float*)d_in[16];
    p.bn2v = (const float*)d_in[17];
    p.bn3g = (const float*)d_in[18];
    p.bn3b = (const float*)d_in[19];
    p.bn3m = (const float*)d_in[20];
    p.bn3v = (const float*)d_in[21];
    p.out  = (float*)d_out;

    char* ws = (char*)d_ws;
    size_t off = 0;
    p.mean1 = (float*)(ws + off); off += (size_t)BB * INP * 4;
    p.msum2 = (float*)(ws + off); off += (size_t)BB * 256 * 4;
    p.msum3 = (float*)(ws + off); off += (size_t)BB * 256 * 4;
    p.zpad  = (unsigned short*)(ws + off); off += 256;
    off = (off + 255) & ~(size_t)255;
    p.act1 = (unsigned short*)(ws + off); off += (size_t)BB * 14 * 8 * 512 * 2;   // 3.67 MB
    p.act2 = (unsigned short*)(ws + off); off += (size_t)BB * 14 * 8 * 512 * 2;   // 3.67 MB
    p.cw2  = (unsigned short*)(ws + off); off += (size_t)BB * 16 * 72 * 512 * 2;  // 37.75 MB
    p.xb   = (unsigned short*)(ws + off); off += (size_t)BB * 14 * 32 * 512 * 2;  // 14.68 MB
    p.wb2  = (unsigned short*)(ws + off); off += (size_t)S2 * NE * 2;             // 9.44 MB
    p.cwX  = (unsigned short*)(ws + off); off += (size_t)BB * S1 * 2;             // 16.78 MB

    // --- Path selection -----------------------------------------------------
    // Cooperative launches are only attempted when the stream is NOT being
    // graph-captured (a failed coop launch during capture invalidates the
    // capture) AND the runtime confirms 512 blocks fit co-resident.
    bool use_coop = false;
    hipStreamCaptureStatus cst = hipStreamCaptureStatusNone;
    if (hipStreamIsCapturing(stream, &cst) == hipSuccess &&
        cst == hipStreamCaptureStatusNone) {
        int maxb = 0;
        if (hipOccupancyMaxActiveBlocksPerMultiprocessor(
                &maxb, (const void*)mega_kernel, 512, 0) == hipSuccess) {
            int dev = 0, ncu = 0;
            hipGetDevice(&dev);
            hipDeviceGetAttribute(&ncu, hipDeviceAttributeMultiprocessorCount, dev);
            if (maxb > 0 && (long long)maxb * ncu >= 512) use_coop = true;
        }
    }
    if (use_coop) {
        void* args[] = {(void*)&p};
        if (hipLaunchCooperativeKernel((void*)mega_kernel, dim3(512), dim3(512),
                                       args, 0, stream) == hipSuccess)
            return;
    }

    // --- Fallback: round-5 multi-kernel path (measured-good, 240.8 us) ------
    pre_kernel<<<2304, 256, 0, stream>>>(p.x, p.xb, p.mean1, p.w2, p.wb2,
                                         p.zpad, p.msum2, p.msum3);

    combine_cont_r<<<dim3(128, 4), 256, 0, stream>>>(p.w1, p.mean1, p.r1w, p.r1b,
                                                     1.0f, INP, p.cwX, S1, 16, 32);
    gemm1_fused<<<dim3(BB, 4, 4), 512, 0, stream>>>(p.xb, p.cwX, p.bn1g, p.bn1b,
                                                    p.bn1m, p.bn1v, p.act1, p.msum2);

    combine_w2_r<<<dim3(288, 4), 256, 0, stream>>>(p.wb2, p.msum2, p.r2w, p.r2b,
                                                   1.0f / (float)HW, p.cw2);
    gemm2_fused<<<dim3(BB, 4, 4), 512, 0, stream>>>(p.act1, p.cw2, p.zpad, p.bn2g,
                                                    p.bn2b, p.bn2m, p.bn2v, p.act2,
                                                    p.msum3);

    combine_cont_r<<<dim3(128, 4), 256, 0, stream>>>(p.w3, p.msum3, p.r3w, p.r3b,
                                                     1.0f / (float)HW, WIDTH,
                                                     p.cwX, S3, 64, 8);
    gemm3_fused<<<dim3(BB, 16), 512, 0, stream>>>(p.act2, p.cwX, p.bn3g, p.bn3b,
                                                  p.bn3m, p.bn3v, p.xb, p.out);
}